// Round 3
// baseline (1180.889 us; speedup 1.0000x reference)
//
#include <hip/hip_runtime.h>
#include <math.h>

#define NN 131071
#define HD 128

__device__ __forceinline__ float sigm(float z) { return 1.0f / (1.0f + __expf(-z)); }
__device__ __forceinline__ float tanh_f(float z) { return 1.0f - 2.0f / (__expf(2.0f * z) + 1.0f); }

// ---------------- leaf level (no children) ----------------
// block = 128 threads (thread j = output column j), MT nodes per block.
template <int MT>
__global__ __launch_bounds__(128) void leaf_kernel(
    const int* __restrict__ feat, const float* __restrict__ emb,
    const float* __restrict__ W_iou, const float* __restrict__ b_iou,
    float* __restrict__ hbuf, float* __restrict__ cbuf, int base)
{
    __shared__ float X[MT][HD];
    const int j = threadIdx.x;
    const int m0 = blockIdx.x * MT;

#pragma unroll
    for (int m = 0; m < MT; ++m) {
        int n = base + m0 + m;
        X[m][j] = emb[(size_t)feat[n] * HD + j];
    }
    __syncthreads();

    float ai[MT], ao[MT], au[MT];
#pragma unroll
    for (int m = 0; m < MT; ++m) {
        ai[m] = b_iou[j];
        ao[m] = b_iou[HD + j];
        au[m] = b_iou[2 * HD + j];
    }

#pragma unroll 4
    for (int k = 0; k < HD; ++k) {
        float wi = W_iou[k * 3 * HD + j];
        float wo = W_iou[k * 3 * HD + HD + j];
        float wu = W_iou[k * 3 * HD + 2 * HD + j];
#pragma unroll
        for (int m = 0; m < MT; ++m) {
            float x = X[m][k];
            ai[m] = fmaf(x, wi, ai[m]);
            ao[m] = fmaf(x, wo, ao[m]);
            au[m] = fmaf(x, wu, au[m]);
        }
    }

#pragma unroll
    for (int m = 0; m < MT; ++m) {
        int n = base + m0 + m;
        float iv = sigm(ai[m]);
        float ov = sigm(ao[m]);
        float uv = tanh_f(au[m]);
        float cv = iv * uv;
        cbuf[(size_t)n * HD + j] = cv;
        hbuf[(size_t)n * HD + j] = ov * tanh_f(cv);
    }
}

// ---------------- internal level ----------------
template <int MT>
__global__ __launch_bounds__(128) void level_kernel(
    const int* __restrict__ feat, const float* __restrict__ emb,
    const float* __restrict__ W_iou, const float* __restrict__ b_iou,
    const float* __restrict__ U_iou,
    const float* __restrict__ W_f, const float* __restrict__ b_f,
    const float* __restrict__ U_f,
    float* __restrict__ hbuf, float* __restrict__ cbuf, int base)
{
    __shared__ float X[MT][HD];
    __shared__ float H1[MT][HD];
    __shared__ float H2[MT][HD];
    const int j = threadIdx.x;
    const int m0 = blockIdx.x * MT;

#pragma unroll
    for (int m = 0; m < MT; ++m) {
        int n = base + m0 + m;
        X[m][j]  = emb[(size_t)feat[n] * HD + j];
        H1[m][j] = hbuf[(size_t)(2 * n + 1) * HD + j];
        H2[m][j] = hbuf[(size_t)(2 * n + 2) * HD + j];
    }
    __syncthreads();

    float ai[MT], ao[MT], au[MT], g1[MT], g2[MT];
#pragma unroll
    for (int m = 0; m < MT; ++m) {
        ai[m] = b_iou[j];
        ao[m] = b_iou[HD + j];
        au[m] = b_iou[2 * HD + j];
        g1[m] = b_f[j];
        g2[m] = b_f[j];
    }

#pragma unroll 2
    for (int k = 0; k < HD; ++k) {
        float wi = W_iou[k * 3 * HD + j];
        float wo = W_iou[k * 3 * HD + HD + j];
        float wu = W_iou[k * 3 * HD + 2 * HD + j];
        float ui = U_iou[k * 3 * HD + j];
        float uo = U_iou[k * 3 * HD + HD + j];
        float uu = U_iou[k * 3 * HD + 2 * HD + j];
        float wf = W_f[k * HD + j];
        float uf = U_f[k * HD + j];
#pragma unroll
        for (int m = 0; m < MT; ++m) {
            float x  = X[m][k];
            float h1 = H1[m][k];
            float h2 = H2[m][k];
            float hs = h1 + h2;
            ai[m] = fmaf(x, wi, fmaf(hs, ui, ai[m]));
            ao[m] = fmaf(x, wo, fmaf(hs, uo, ao[m]));
            au[m] = fmaf(x, wu, fmaf(hs, uu, au[m]));
            g1[m] = fmaf(x, wf, fmaf(h1, uf, g1[m]));
            g2[m] = fmaf(x, wf, fmaf(h2, uf, g2[m]));
        }
    }

#pragma unroll
    for (int m = 0; m < MT; ++m) {
        int n = base + m0 + m;
        float iv = sigm(ai[m]);
        float ov = sigm(ao[m]);
        float uv = tanh_f(au[m]);
        float f1 = sigm(g1[m]);
        float f2 = sigm(g2[m]);
        float c1 = cbuf[(size_t)(2 * n + 1) * HD + j];
        float c2 = cbuf[(size_t)(2 * n + 2) * HD + j];
        float cn = fmaf(iv, uv, fmaf(f1, c1, f2 * c2));
        cbuf[(size_t)n * HD + j] = cn;
        hbuf[(size_t)n * HD + j] = ov * tanh_f(cn);
    }
}

extern "C" void kernel_launch(void* const* d_in, const int* in_sizes, int n_in,
                              void* d_out, int out_size, void* d_ws, size_t ws_size,
                              hipStream_t stream)
{
    const int*   feat  = (const int*)d_in[0];
    const float* emb   = (const float*)d_in[4];
    const float* W_iou = (const float*)d_in[5];
    const float* b_iou = (const float*)d_in[6];
    const float* U_iou = (const float*)d_in[7];
    const float* W_f   = (const float*)d_in[8];
    const float* b_f   = (const float*)d_in[9];
    const float* U_f   = (const float*)d_in[10];

    float* hbuf = (float*)d_out;
    float* cbuf = hbuf + (size_t)NN * HD;

    // level 0: leaves at depth 16 -> base = 65535, count = 65536
    leaf_kernel<16><<<65536 / 16, 128, 0, stream>>>(feat, emb, W_iou, b_iou, hbuf, cbuf, 65535);

    for (int lvl = 1; lvl <= 16; ++lvl) {
        const int d     = 16 - lvl;
        const int count = 1 << d;
        const int base  = count - 1;
        if (count >= 16) {
            level_kernel<16><<<count / 16, 128, 0, stream>>>(
                feat, emb, W_iou, b_iou, U_iou, W_f, b_f, U_f, hbuf, cbuf, base);
        } else if (count == 8) {
            level_kernel<8><<<1, 128, 0, stream>>>(
                feat, emb, W_iou, b_iou, U_iou, W_f, b_f, U_f, hbuf, cbuf, base);
        } else if (count == 4) {
            level_kernel<4><<<1, 128, 0, stream>>>(
                feat, emb, W_iou, b_iou, U_iou, W_f, b_f, U_f, hbuf, cbuf, base);
        } else if (count == 2) {
            level_kernel<2><<<1, 128, 0, stream>>>(
                feat, emb, W_iou, b_iou, U_iou, W_f, b_f, U_f, hbuf, cbuf, base);
        } else {
            level_kernel<1><<<1, 128, 0, stream>>>(
                feat, emb, W_iou, b_iou, U_iou, W_f, b_f, U_f, hbuf, cbuf, base);
        }
    }
}

// Round 4
// 775.197 us; speedup vs baseline: 1.5233x; 1.5233x over previous
//
#include <hip/hip_runtime.h>
#include <math.h>

#define NN 131071
#define HD 128

typedef short bf16x8 __attribute__((ext_vector_type(8)));
typedef unsigned short u16x8 __attribute__((ext_vector_type(8)));
typedef float f32x4 __attribute__((ext_vector_type(4)));

__device__ __forceinline__ float sigm(float z) { return 1.0f / (1.0f + __expf(-z)); }
__device__ __forceinline__ float tanh_f(float z) { return 1.0f - 2.0f / (__expf(2.0f * z) + 1.0f); }

__device__ __forceinline__ unsigned short f2bf(float f) {
    unsigned u = __float_as_uint(f);
    u += 0x7FFFu + ((u >> 16) & 1u);
    return (unsigned short)(u >> 16);
}

__device__ __forceinline__ f32x4 mfma16(bf16x8 a, bf16x8 b, f32x4 c) {
    return __builtin_amdgcn_mfma_f32_16x16x32_bf16(a, b, c, 0, 0, 0);
}

__device__ __forceinline__ float4 addf4(float4 a, float4 b) {
    float4 r; r.x = a.x + b.x; r.y = a.y + b.y; r.z = a.z + b.z; r.w = a.w + b.w; return r;
}

// store 8 f32 (two float4) as bf16 chunk cc (16B) of row r, XOR-swizzled
__device__ __forceinline__ void lds_store8(unsigned short* region, int r, int cc, float4 a, float4 b) {
    u16x8 p;
    p[0] = f2bf(a.x); p[1] = f2bf(a.y); p[2] = f2bf(a.z); p[3] = f2bf(a.w);
    p[4] = f2bf(b.x); p[5] = f2bf(b.y); p[6] = f2bf(b.z); p[7] = f2bf(b.w);
    *(u16x8*)&region[r * HD + ((cc ^ (r & 7)) << 3)] = p;
}

// A-fragment: row, k-chunk = kk*4 + klane (16B), swizzled
__device__ __forceinline__ bf16x8 lds_frag(const unsigned short* region, int row, int kk, int kl) {
    int cc = kk * 4 + kl;
    return *(const bf16x8*)&region[row * HD + ((cc ^ (row & 7)) << 3)];
}

// B-fragment from transposed bf16 weights Bt[col][k]
__device__ __forceinline__ bf16x8 bload(const unsigned short* Wt, int col, int kk, int kl) {
    return *(const bf16x8*)&Wt[(size_t)col * HD + kk * 32 + kl * 8];
}

// ---- build transposed bf16 weights in ws: [Wt_iou(384) | Ut_iou(384) | Wt_f(128) | Ut_f(128)][128]
__global__ __launch_bounds__(256) void build_wt(
    const float* __restrict__ W_iou, const float* __restrict__ U_iou,
    const float* __restrict__ W_f, const float* __restrict__ U_f,
    unsigned short* __restrict__ ws)
{
    int idx = blockIdx.x * 256 + threadIdx.x;  // 0..131071
    int k = idx & 127;
    int c = idx >> 7;  // 0..1023
    float v;
    if (c < 384)       v = W_iou[k * 384 + c];
    else if (c < 768)  v = U_iou[k * 384 + (c - 384)];
    else if (c < 896)  v = W_f[k * HD + (c - 768)];
    else               v = U_f[k * HD + (c - 896)];
    ws[idx] = f2bf(v);
}

// ---- leaf: iou = x@W_iou + b; c = i*u; h = o*tanh(c). 64 nodes/block, 512 thr.
__global__ __launch_bounds__(512) void leaf_mfma(
    const int* __restrict__ feat, const float* __restrict__ emb,
    const unsigned short* __restrict__ wsw, const float* __restrict__ b_iou,
    float* __restrict__ hbuf, float* __restrict__ cbuf, int base)
{
    __shared__ unsigned short ldsx[64 * HD];
    const int t = threadIdx.x;
    const int m0 = blockIdx.x * 64;
    {
        const int r = t >> 3, c8 = t & 7;
        const int n = base + m0 + r;
        const float* src = emb + (size_t)feat[n] * HD + c8 * 16;
        float4 a0 = *(const float4*)(src + 0);
        float4 a1 = *(const float4*)(src + 4);
        float4 a2 = *(const float4*)(src + 8);
        float4 a3 = *(const float4*)(src + 12);
        lds_store8(ldsx, r, c8 * 2 + 0, a0, a1);
        lds_store8(ldsx, r, c8 * 2 + 1, a2, a3);
    }
    __syncthreads();

    const int lane = t & 63, w = t >> 6;
    const int mt = w & 3, half = w >> 2;
    const int l15 = lane & 15, kl = lane >> 4;
    const int arow = mt * 16 + l15;

    f32x4 zero = {0.f, 0.f, 0.f, 0.f};
    f32x4 ai[4], ao[4], au[4];
#pragma unroll
    for (int jt = 0; jt < 4; ++jt) { ai[jt] = zero; ao[jt] = zero; au[jt] = zero; }

#pragma unroll
    for (int kk = 0; kk < 4; ++kk) {
        bf16x8 a = lds_frag(ldsx, arow, kk, kl);
#pragma unroll
        for (int jt = 0; jt < 4; ++jt) {
            int j = half * 64 + jt * 16 + l15;
            ai[jt] = mfma16(a, bload(wsw, j, kk, kl), ai[jt]);
            ao[jt] = mfma16(a, bload(wsw, HD + j, kk, kl), ao[jt]);
            au[jt] = mfma16(a, bload(wsw, 2 * HD + j, kk, kl), au[jt]);
        }
    }

#pragma unroll
    for (int jt = 0; jt < 4; ++jt) {
        int j = half * 64 + jt * 16 + l15;
        float bi = b_iou[j], bo = b_iou[HD + j], bu = b_iou[2 * HD + j];
#pragma unroll
        for (int r = 0; r < 4; ++r) {
            int n = base + m0 + mt * 16 + kl * 4 + r;
            float iv = sigm(ai[jt][r] + bi);
            float ov = sigm(ao[jt][r] + bo);
            float uv = tanh_f(au[jt][r] + bu);
            float cv = iv * uv;
            cbuf[(size_t)n * HD + j] = cv;
            hbuf[(size_t)n * HD + j] = ov * tanh_f(cv);
        }
    }
}

// ---- internal level (count >= 128): full TreeLSTM node update. 64 nodes/block.
__global__ __launch_bounds__(512) void level_mfma(
    const int* __restrict__ feat, const float* __restrict__ emb,
    const unsigned short* __restrict__ wsw,
    const float* __restrict__ b_iou, const float* __restrict__ b_f,
    float* __restrict__ hbuf, float* __restrict__ cbuf, int base)
{
    __shared__ unsigned short lds[4 * 64 * HD];
    unsigned short* ldsx  = lds;
    unsigned short* ldshs = lds + 8192;
    unsigned short* ldsh1 = lds + 16384;
    unsigned short* ldsh2 = lds + 24576;

    const unsigned short* WT_IOU = wsw;
    const unsigned short* UT_IOU = wsw + 384 * HD;
    const unsigned short* WT_F   = wsw + 768 * HD;
    const unsigned short* UT_F   = wsw + 896 * HD;

    const int t = threadIdx.x;
    const int m0 = blockIdx.x * 64;
    {
        const int r = t >> 3, c8 = t & 7;
        const int n = base + m0 + r;
        const float* sx = emb + (size_t)feat[n] * HD + c8 * 16;
        float4 x0 = *(const float4*)(sx + 0);
        float4 x1 = *(const float4*)(sx + 4);
        float4 x2 = *(const float4*)(sx + 8);
        float4 x3 = *(const float4*)(sx + 12);
        lds_store8(ldsx, r, c8 * 2 + 0, x0, x1);
        lds_store8(ldsx, r, c8 * 2 + 1, x2, x3);

        const float* s1 = hbuf + (size_t)(2 * n + 1) * HD + c8 * 16;
        const float* s2 = hbuf + (size_t)(2 * n + 2) * HD + c8 * 16;
        float4 p0 = *(const float4*)(s1 + 0);
        float4 p1 = *(const float4*)(s1 + 4);
        float4 p2 = *(const float4*)(s1 + 8);
        float4 p3 = *(const float4*)(s1 + 12);
        float4 q0 = *(const float4*)(s2 + 0);
        float4 q1 = *(const float4*)(s2 + 4);
        float4 q2 = *(const float4*)(s2 + 8);
        float4 q3 = *(const float4*)(s2 + 12);
        lds_store8(ldsh1, r, c8 * 2 + 0, p0, p1);
        lds_store8(ldsh1, r, c8 * 2 + 1, p2, p3);
        lds_store8(ldsh2, r, c8 * 2 + 0, q0, q1);
        lds_store8(ldsh2, r, c8 * 2 + 1, q2, q3);
        lds_store8(ldshs, r, c8 * 2 + 0, addf4(p0, q0), addf4(p1, q1));
        lds_store8(ldshs, r, c8 * 2 + 1, addf4(p2, q2), addf4(p3, q3));
    }
    __syncthreads();

    const int lane = t & 63, w = t >> 6;
    const int mt = w & 3, half = w >> 2;
    const int l15 = lane & 15, kl = lane >> 4;
    const int arow = mt * 16 + l15;

    f32x4 zero = {0.f, 0.f, 0.f, 0.f};
    f32x4 ai[4], ao[4], au[4], af1[4], af2[4];
#pragma unroll
    for (int jt = 0; jt < 4; ++jt) { ai[jt] = zero; ao[jt] = zero; au[jt] = zero; af1[jt] = zero; af2[jt] = zero; }

    // K 0-127: x against W-weights
#pragma unroll
    for (int kk = 0; kk < 4; ++kk) {
        bf16x8 a = lds_frag(ldsx, arow, kk, kl);
#pragma unroll
        for (int jt = 0; jt < 4; ++jt) {
            int j = half * 64 + jt * 16 + l15;
            ai[jt] = mfma16(a, bload(WT_IOU, j, kk, kl), ai[jt]);
            ao[jt] = mfma16(a, bload(WT_IOU, HD + j, kk, kl), ao[jt]);
            au[jt] = mfma16(a, bload(WT_IOU, 2 * HD + j, kk, kl), au[jt]);
            bf16x8 bw = bload(WT_F, j, kk, kl);
            af1[jt] = mfma16(a, bw, af1[jt]);
            af2[jt] = mfma16(a, bw, af2[jt]);
        }
    }
    // K 128-255: hs/h1/h2 against U-weights
#pragma unroll
    for (int kk = 0; kk < 4; ++kk) {
        bf16x8 ahs = lds_frag(ldshs, arow, kk, kl);
        bf16x8 ah1 = lds_frag(ldsh1, arow, kk, kl);
        bf16x8 ah2 = lds_frag(ldsh2, arow, kk, kl);
#pragma unroll
        for (int jt = 0; jt < 4; ++jt) {
            int j = half * 64 + jt * 16 + l15;
            ai[jt] = mfma16(ahs, bload(UT_IOU, j, kk, kl), ai[jt]);
            ao[jt] = mfma16(ahs, bload(UT_IOU, HD + j, kk, kl), ao[jt]);
            au[jt] = mfma16(ahs, bload(UT_IOU, 2 * HD + j, kk, kl), au[jt]);
            bf16x8 bu = bload(UT_F, j, kk, kl);
            af1[jt] = mfma16(ah1, bu, af1[jt]);
            af2[jt] = mfma16(ah2, bu, af2[jt]);
        }
    }

#pragma unroll
    for (int jt = 0; jt < 4; ++jt) {
        int j = half * 64 + jt * 16 + l15;
        float bi = b_iou[j], bo = b_iou[HD + j], bu = b_iou[2 * HD + j], bf = b_f[j];
#pragma unroll
        for (int r = 0; r < 4; ++r) {
            int n = base + m0 + mt * 16 + kl * 4 + r;
            float iv = sigm(ai[jt][r] + bi);
            float ov = sigm(ao[jt][r] + bo);
            float uv = tanh_f(au[jt][r] + bu);
            float f1 = sigm(af1[jt][r] + bf);
            float f2 = sigm(af2[jt][r] + bf);
            float c1 = cbuf[(size_t)(2 * n + 1) * HD + j];
            float c2 = cbuf[(size_t)(2 * n + 2) * HD + j];
            float cn = fmaf(iv, uv, fmaf(f1, c1, f2 * c2));
            cbuf[(size_t)n * HD + j] = cn;
            hbuf[(size_t)n * HD + j] = ov * tanh_f(cn);
        }
    }
}

// ---------------- scalar fallback for small levels (count < 128) ----------------
template <int MT>
__global__ __launch_bounds__(128) void level_kernel(
    const int* __restrict__ feat, const float* __restrict__ emb,
    const float* __restrict__ W_iou, const float* __restrict__ b_iou,
    const float* __restrict__ U_iou,
    const float* __restrict__ W_f, const float* __restrict__ b_f,
    const float* __restrict__ U_f,
    float* __restrict__ hbuf, float* __restrict__ cbuf, int base)
{
    __shared__ float X[MT][HD];
    __shared__ float H1[MT][HD];
    __shared__ float H2[MT][HD];
    const int j = threadIdx.x;
    const int m0 = blockIdx.x * MT;

#pragma unroll
    for (int m = 0; m < MT; ++m) {
        int n = base + m0 + m;
        X[m][j]  = emb[(size_t)feat[n] * HD + j];
        H1[m][j] = hbuf[(size_t)(2 * n + 1) * HD + j];
        H2[m][j] = hbuf[(size_t)(2 * n + 2) * HD + j];
    }
    __syncthreads();

    float ai[MT], ao[MT], au[MT], g1[MT], g2[MT];
#pragma unroll
    for (int m = 0; m < MT; ++m) {
        ai[m] = b_iou[j];
        ao[m] = b_iou[HD + j];
        au[m] = b_iou[2 * HD + j];
        g1[m] = b_f[j];
        g2[m] = b_f[j];
    }

#pragma unroll 2
    for (int k = 0; k < HD; ++k) {
        float wi = W_iou[k * 3 * HD + j];
        float wo = W_iou[k * 3 * HD + HD + j];
        float wu = W_iou[k * 3 * HD + 2 * HD + j];
        float ui = U_iou[k * 3 * HD + j];
        float uo = U_iou[k * 3 * HD + HD + j];
        float uu = U_iou[k * 3 * HD + 2 * HD + j];
        float wf = W_f[k * HD + j];
        float uf = U_f[k * HD + j];
#pragma unroll
        for (int m = 0; m < MT; ++m) {
            float x  = X[m][k];
            float h1 = H1[m][k];
            float h2 = H2[m][k];
            float hs = h1 + h2;
            ai[m] = fmaf(x, wi, fmaf(hs, ui, ai[m]));
            ao[m] = fmaf(x, wo, fmaf(hs, uo, ao[m]));
            au[m] = fmaf(x, wu, fmaf(hs, uu, au[m]));
            g1[m] = fmaf(x, wf, fmaf(h1, uf, g1[m]));
            g2[m] = fmaf(x, wf, fmaf(h2, uf, g2[m]));
        }
    }

#pragma unroll
    for (int m = 0; m < MT; ++m) {
        int n = base + m0 + m;
        float iv = sigm(ai[m]);
        float ov = sigm(ao[m]);
        float uv = tanh_f(au[m]);
        float f1 = sigm(g1[m]);
        float f2 = sigm(g2[m]);
        float c1 = cbuf[(size_t)(2 * n + 1) * HD + j];
        float c2 = cbuf[(size_t)(2 * n + 2) * HD + j];
        float cn = fmaf(iv, uv, fmaf(f1, c1, f2 * c2));
        cbuf[(size_t)n * HD + j] = cn;
        hbuf[(size_t)n * HD + j] = ov * tanh_f(cn);
    }
}

extern "C" void kernel_launch(void* const* d_in, const int* in_sizes, int n_in,
                              void* d_out, int out_size, void* d_ws, size_t ws_size,
                              hipStream_t stream)
{
    const int*   feat  = (const int*)d_in[0];
    const float* emb   = (const float*)d_in[4];
    const float* W_iou = (const float*)d_in[5];
    const float* b_iou = (const float*)d_in[6];
    const float* U_iou = (const float*)d_in[7];
    const float* W_f   = (const float*)d_in[8];
    const float* b_f   = (const float*)d_in[9];
    const float* U_f   = (const float*)d_in[10];

    float* hbuf = (float*)d_out;
    float* cbuf = hbuf + (size_t)NN * HD;
    unsigned short* wsw = (unsigned short*)d_ws;

    // transposed bf16 weights (256 KB in d_ws), rebuilt every call (deterministic)
    build_wt<<<512, 256, 0, stream>>>(W_iou, U_iou, W_f, U_f, wsw);

    // leaves: 65536 nodes at base 65535
    leaf_mfma<<<1024, 512, 0, stream>>>(feat, emb, wsw, b_iou, hbuf, cbuf, 65535);

    for (int lvl = 1; lvl <= 16; ++lvl) {
        const int d     = 16 - lvl;
        const int count = 1 << d;
        const int base  = count - 1;
        if (count >= 128) {
            level_mfma<<<count / 64, 512, 0, stream>>>(
                feat, emb, wsw, b_iou, b_f, hbuf, cbuf, base);
        } else if (count >= 16) {
            level_kernel<16><<<count / 16, 128, 0, stream>>>(
                feat, emb, W_iou, b_iou, U_iou, W_f, b_f, U_f, hbuf, cbuf, base);
        } else if (count == 8) {
            level_kernel<8><<<1, 128, 0, stream>>>(
                feat, emb, W_iou, b_iou, U_iou, W_f, b_f, U_f, hbuf, cbuf, base);
        } else if (count == 4) {
            level_kernel<4><<<1, 128, 0, stream>>>(
                feat, emb, W_iou, b_iou, U_iou, W_f, b_f, U_f, hbuf, cbuf, base);
        } else if (count == 2) {
            level_kernel<2><<<1, 128, 0, stream>>>(
                feat, emb, W_iou, b_iou, U_iou, W_f, b_f, U_f, hbuf, cbuf, base);
        } else {
            level_kernel<1><<<1, 128, 0, stream>>>(
                feat, emb, W_iou, b_iou, U_iou, W_f, b_f, U_f, hbuf, cbuf, base);
        }
    }
}

// Round 5
// 363.821 us; speedup vs baseline: 3.2458x; 2.1307x over previous
//
#include <hip/hip_runtime.h>
#include <math.h>

#define NN 131071
#define HD 128
#define N_INTERNAL 65535
#define LEAF_BASE 65535

typedef short bf16x8 __attribute__((ext_vector_type(8)));
typedef unsigned short u16x8 __attribute__((ext_vector_type(8)));
typedef float f32x4 __attribute__((ext_vector_type(4)));

__device__ __forceinline__ float sigm(float z) { return 1.0f / (1.0f + __expf(-z)); }
__device__ __forceinline__ float tanh_f(float z) { return 1.0f - 2.0f / (__expf(2.0f * z) + 1.0f); }

__device__ __forceinline__ unsigned short f2bf(float f) {
    unsigned u = __float_as_uint(f);
    u += 0x7FFFu + ((u >> 16) & 1u);
    return (unsigned short)(u >> 16);
}

__device__ __forceinline__ f32x4 mfma16(bf16x8 a, bf16x8 b, f32x4 c) {
    return __builtin_amdgcn_mfma_f32_16x16x32_bf16(a, b, c, 0, 0, 0);
}

__device__ __forceinline__ float4 addf4(float4 a, float4 b) {
    float4 r; r.x = a.x + b.x; r.y = a.y + b.y; r.z = a.z + b.z; r.w = a.w + b.w; return r;
}

// store 8 f32 (two float4) as bf16 chunk cc (16B) of row r, XOR-swizzled
__device__ __forceinline__ void lds_store8(unsigned short* region, int r, int cc, float4 a, float4 b) {
    u16x8 p;
    p[0] = f2bf(a.x); p[1] = f2bf(a.y); p[2] = f2bf(a.z); p[3] = f2bf(a.w);
    p[4] = f2bf(b.x); p[5] = f2bf(b.y); p[6] = f2bf(b.z); p[7] = f2bf(b.w);
    *(u16x8*)&region[r * HD + ((cc ^ (r & 7)) << 3)] = p;
}

// A-fragment: row, k-step ks, k-lane kl (16B), swizzled
__device__ __forceinline__ bf16x8 lds_frag(const unsigned short* region, int row, int ks, int kl) {
    int cc = ks * 4 + kl;
    return *(const bf16x8*)&region[row * HD + ((cc ^ (row & 7)) << 3)];
}

// B-fragment from fragment-order-packed weights: contiguous 16B per lane
__device__ __forceinline__ bf16x8 frag2(const unsigned short* M, int ct, int ks, int lane) {
    return *(const bf16x8*)&M[(((ct * 4 + ks) * 64) + lane) * 8];
}

// ---- pack bf16 weights in MFMA-fragment order.
// WT2 (matrix 0): cols 0:384 = W_iou, 384:512 = W_f.  UT2 (matrix 1): U_iou | U_f.
// frag f: value[e] = M[k = ks*32 + (lane>>4)*8 + e][col = ct*16 + (lane&15)]
__global__ __launch_bounds__(256) void build_packed(
    const float* __restrict__ W_iou, const float* __restrict__ U_iou,
    const float* __restrict__ W_f, const float* __restrict__ U_f,
    unsigned short* __restrict__ ws)
{
    int f = blockIdx.x * 256 + threadIdx.x;   // 0..16383
    int mat = f >> 13;
    int rem = f & 8191;
    int ct = rem >> 8;
    int ks = (rem >> 6) & 3;
    int lane = rem & 63;
    int col = ct * 16 + (lane & 15);
    int k0 = ks * 32 + (lane >> 4) * 8;
    u16x8 out;
#pragma unroll
    for (int e = 0; e < 8; ++e) {
        int k = k0 + e;
        float v;
        if (mat == 0) v = (col < 384) ? W_iou[k * 384 + col] : W_f[k * HD + (col - 384)];
        else          v = (col < 384) ? U_iou[k * 384 + col] : U_f[k * HD + (col - 384)];
        out[e] = f2bf(v);
    }
    *(u16x8*)&ws[(size_t)f * 8] = out;
}

// ---- XP precompute for internal nodes + fused leaf gate math.
// 64 nodes/block, 512 threads, 8 waves = (jq 0..3) x (mh 0..1).
__global__ __launch_bounds__(512) void xp_leaf_kernel(
    const int* __restrict__ feat, const float* __restrict__ emb,
    const unsigned short* __restrict__ WT2,
    const float* __restrict__ b_iou, const float* __restrict__ b_f,
    float* __restrict__ XP, float* __restrict__ hbuf, float* __restrict__ cbuf)
{
    __shared__ unsigned short ldsx[64 * HD];
    const int t = threadIdx.x;
    const int m0 = blockIdx.x * 64;
    {
        int r = t >> 3, c8 = t & 7;
        int n = m0 + r;
        int nn = n < NN ? n : 0;
        const float* sx = emb + (size_t)feat[nn] * HD + c8 * 16;
        float4 x0 = *(const float4*)(sx + 0);
        float4 x1 = *(const float4*)(sx + 4);
        float4 x2 = *(const float4*)(sx + 8);
        float4 x3 = *(const float4*)(sx + 12);
        lds_store8(ldsx, r, c8 * 2 + 0, x0, x1);
        lds_store8(ldsx, r, c8 * 2 + 1, x2, x3);
    }
    __syncthreads();

    const int lane = t & 63, w = t >> 6;
    const int jq = w & 3, mh = w >> 2;
    const int l15 = lane & 15, kl = lane >> 4;

    f32x4 zero = {0.f, 0.f, 0.f, 0.f};
    f32x4 acc[4][2][2];   // [gate i,o,u,f][m-tile][jt]
#pragma unroll
    for (int g = 0; g < 4; ++g)
#pragma unroll
        for (int mp = 0; mp < 2; ++mp)
#pragma unroll
            for (int jt = 0; jt < 2; ++jt) acc[g][mp][jt] = zero;

#pragma unroll
    for (int ks = 0; ks < 4; ++ks) {
        bf16x8 a0 = lds_frag(ldsx, (mh * 2 + 0) * 16 + l15, ks, kl);
        bf16x8 a1 = lds_frag(ldsx, (mh * 2 + 1) * 16 + l15, ks, kl);
#pragma unroll
        for (int g = 0; g < 4; ++g) {
#pragma unroll
            for (int jt = 0; jt < 2; ++jt) {
                bf16x8 b = frag2(WT2, g * 8 + jq * 2 + jt, ks, lane);
                acc[g][0][jt] = mfma16(a0, b, acc[g][0][jt]);
                acc[g][1][jt] = mfma16(a1, b, acc[g][1][jt]);
            }
        }
    }

#pragma unroll
    for (int mp = 0; mp < 2; ++mp) {
#pragma unroll
        for (int jt = 0; jt < 2; ++jt) {
            int j = jq * 32 + jt * 16 + l15;
            int nb = m0 + (mh * 2 + mp) * 16 + kl * 4;
            float bi = b_iou[j], bo = b_iou[HD + j], bu = b_iou[2 * HD + j], bf = b_f[j];
#pragma unroll
            for (int r = 0; r < 4; ++r) {
                int n = nb + r;
                if (n >= NN) continue;
                if (n >= LEAF_BASE) {
                    float iv = sigm(acc[0][mp][jt][r] + bi);
                    float ov = sigm(acc[1][mp][jt][r] + bo);
                    float uv = tanh_f(acc[2][mp][jt][r] + bu);
                    float cv = iv * uv;
                    cbuf[(size_t)n * HD + j] = cv;
                    hbuf[(size_t)n * HD + j] = ov * tanh_f(cv);
                } else {
                    float* xp = XP + (size_t)n * 512;
                    xp[j]          = acc[0][mp][jt][r] + bi;
                    xp[128 + j]    = acc[1][mp][jt][r] + bo;
                    xp[256 + j]    = acc[2][mp][jt][r] + bu;
                    xp[384 + j]    = acc[3][mp][jt][r] + bf;
                }
            }
        }
    }
}

// ---- internal level: U-projections + gates, fused. 64 nodes/block (masked).
__global__ __launch_bounds__(512) void level_u_kernel(
    const unsigned short* __restrict__ UT2, const float* __restrict__ XP,
    float* __restrict__ hbuf, float* __restrict__ cbuf, int base, int count)
{
    __shared__ unsigned short lds[3 * 64 * HD];
    unsigned short* ldshs = lds;
    unsigned short* ldsh1 = lds + 8192;
    unsigned short* ldsh2 = lds + 16384;

    const int t = threadIdx.x;
    const int m0 = blockIdx.x * 64;
    {
        int r = t >> 3, c8 = t & 7;
        int row = m0 + r;
        int n = base + (row < count ? row : 0);
        const float* s1 = hbuf + (size_t)(2 * n + 1) * HD + c8 * 16;
        const float* s2 = hbuf + (size_t)(2 * n + 2) * HD + c8 * 16;
        float4 p0 = *(const float4*)(s1 + 0);
        float4 p1 = *(const float4*)(s1 + 4);
        float4 p2 = *(const float4*)(s1 + 8);
        float4 p3 = *(const float4*)(s1 + 12);
        float4 q0 = *(const float4*)(s2 + 0);
        float4 q1 = *(const float4*)(s2 + 4);
        float4 q2 = *(const float4*)(s2 + 8);
        float4 q3 = *(const float4*)(s2 + 12);
        lds_store8(ldsh1, r, c8 * 2 + 0, p0, p1);
        lds_store8(ldsh1, r, c8 * 2 + 1, p2, p3);
        lds_store8(ldsh2, r, c8 * 2 + 0, q0, q1);
        lds_store8(ldsh2, r, c8 * 2 + 1, q2, q3);
        lds_store8(ldshs, r, c8 * 2 + 0, addf4(p0, q0), addf4(p1, q1));
        lds_store8(ldshs, r, c8 * 2 + 1, addf4(p2, q2), addf4(p3, q3));
    }
    __syncthreads();

    const int lane = t & 63, w = t >> 6;
    const int jq = w & 3, mh = w >> 2;
    const int l15 = lane & 15, kl = lane >> 4;

    f32x4 zero = {0.f, 0.f, 0.f, 0.f};
    f32x4 acc[5][2][2];   // i,o,u,f1,f2
#pragma unroll
    for (int g = 0; g < 5; ++g)
#pragma unroll
        for (int mp = 0; mp < 2; ++mp)
#pragma unroll
            for (int jt = 0; jt < 2; ++jt) acc[g][mp][jt] = zero;

#pragma unroll
    for (int ks = 0; ks < 4; ++ks) {
        bf16x8 ahs0 = lds_frag(ldshs, (mh * 2 + 0) * 16 + l15, ks, kl);
        bf16x8 ahs1 = lds_frag(ldshs, (mh * 2 + 1) * 16 + l15, ks, kl);
        bf16x8 ah10 = lds_frag(ldsh1, (mh * 2 + 0) * 16 + l15, ks, kl);
        bf16x8 ah11 = lds_frag(ldsh1, (mh * 2 + 1) * 16 + l15, ks, kl);
        bf16x8 ah20 = lds_frag(ldsh2, (mh * 2 + 0) * 16 + l15, ks, kl);
        bf16x8 ah21 = lds_frag(ldsh2, (mh * 2 + 1) * 16 + l15, ks, kl);
#pragma unroll
        for (int jt = 0; jt < 2; ++jt) {
            bf16x8 Bi = frag2(UT2,  0 + jq * 2 + jt, ks, lane);
            bf16x8 Bo = frag2(UT2,  8 + jq * 2 + jt, ks, lane);
            bf16x8 Bu = frag2(UT2, 16 + jq * 2 + jt, ks, lane);
            bf16x8 Bf = frag2(UT2, 24 + jq * 2 + jt, ks, lane);
            acc[0][0][jt] = mfma16(ahs0, Bi, acc[0][0][jt]);
            acc[0][1][jt] = mfma16(ahs1, Bi, acc[0][1][jt]);
            acc[1][0][jt] = mfma16(ahs0, Bo, acc[1][0][jt]);
            acc[1][1][jt] = mfma16(ahs1, Bo, acc[1][1][jt]);
            acc[2][0][jt] = mfma16(ahs0, Bu, acc[2][0][jt]);
            acc[2][1][jt] = mfma16(ahs1, Bu, acc[2][1][jt]);
            acc[3][0][jt] = mfma16(ah10, Bf, acc[3][0][jt]);
            acc[3][1][jt] = mfma16(ah11, Bf, acc[3][1][jt]);
            acc[4][0][jt] = mfma16(ah20, Bf, acc[4][0][jt]);
            acc[4][1][jt] = mfma16(ah21, Bf, acc[4][1][jt]);
        }
    }

#pragma unroll
    for (int mp = 0; mp < 2; ++mp) {
#pragma unroll
        for (int jt = 0; jt < 2; ++jt) {
            int j = jq * 32 + jt * 16 + l15;
#pragma unroll
            for (int r = 0; r < 4; ++r) {
                int row = m0 + (mh * 2 + mp) * 16 + kl * 4 + r;
                if (row >= count) continue;
                int n = base + row;
                const float* xp = XP + (size_t)n * 512;
                float iv = sigm(acc[0][mp][jt][r] + xp[j]);
                float ov = sigm(acc[1][mp][jt][r] + xp[128 + j]);
                float uv = tanh_f(acc[2][mp][jt][r] + xp[256 + j]);
                float f1 = sigm(acc[3][mp][jt][r] + xp[384 + j]);
                float f2 = sigm(acc[4][mp][jt][r] + xp[384 + j]);
                float c1 = cbuf[(size_t)(2 * n + 1) * HD + j];
                float c2 = cbuf[(size_t)(2 * n + 2) * HD + j];
                float cn = fmaf(iv, uv, fmaf(f1, c1, f2 * c2));
                cbuf[(size_t)n * HD + j] = cn;
                hbuf[(size_t)n * HD + j] = ov * tanh_f(cn);
            }
        }
    }
}

// ---------------- scalar fallback (known-correct R3 path, used only if ws too small) ----------------
template <int MT>
__global__ __launch_bounds__(128) void leaf_kernel(
    const int* __restrict__ feat, const float* __restrict__ emb,
    const float* __restrict__ W_iou, const float* __restrict__ b_iou,
    float* __restrict__ hbuf, float* __restrict__ cbuf, int base)
{
    __shared__ float X[MT][HD];
    const int j = threadIdx.x;
    const int m0 = blockIdx.x * MT;
#pragma unroll
    for (int m = 0; m < MT; ++m) {
        int n = base + m0 + m;
        X[m][j] = emb[(size_t)feat[n] * HD + j];
    }
    __syncthreads();
    float ai[MT], ao[MT], au[MT];
#pragma unroll
    for (int m = 0; m < MT; ++m) {
        ai[m] = b_iou[j]; ao[m] = b_iou[HD + j]; au[m] = b_iou[2 * HD + j];
    }
#pragma unroll 4
    for (int k = 0; k < HD; ++k) {
        float wi = W_iou[k * 3 * HD + j];
        float wo = W_iou[k * 3 * HD + HD + j];
        float wu = W_iou[k * 3 * HD + 2 * HD + j];
#pragma unroll
        for (int m = 0; m < MT; ++m) {
            float x = X[m][k];
            ai[m] = fmaf(x, wi, ai[m]); ao[m] = fmaf(x, wo, ao[m]); au[m] = fmaf(x, wu, au[m]);
        }
    }
#pragma unroll
    for (int m = 0; m < MT; ++m) {
        int n = base + m0 + m;
        float iv = sigm(ai[m]); float ov = sigm(ao[m]); float uv = tanh_f(au[m]);
        float cv = iv * uv;
        cbuf[(size_t)n * HD + j] = cv;
        hbuf[(size_t)n * HD + j] = ov * tanh_f(cv);
    }
}

template <int MT>
__global__ __launch_bounds__(128) void level_kernel(
    const int* __restrict__ feat, const float* __restrict__ emb,
    const float* __restrict__ W_iou, const float* __restrict__ b_iou,
    const float* __restrict__ U_iou,
    const float* __restrict__ W_f, const float* __restrict__ b_f,
    const float* __restrict__ U_f,
    float* __restrict__ hbuf, float* __restrict__ cbuf, int base)
{
    __shared__ float X[MT][HD];
    __shared__ float H1[MT][HD];
    __shared__ float H2[MT][HD];
    const int j = threadIdx.x;
    const int m0 = blockIdx.x * MT;
#pragma unroll
    for (int m = 0; m < MT; ++m) {
        int n = base + m0 + m;
        X[m][j]  = emb[(size_t)feat[n] * HD + j];
        H1[m][j] = hbuf[(size_t)(2 * n + 1) * HD + j];
        H2[m][j] = hbuf[(size_t)(2 * n + 2) * HD + j];
    }
    __syncthreads();
    float ai[MT], ao[MT], au[MT], g1[MT], g2[MT];
#pragma unroll
    for (int m = 0; m < MT; ++m) {
        ai[m] = b_iou[j]; ao[m] = b_iou[HD + j]; au[m] = b_iou[2 * HD + j];
        g1[m] = b_f[j]; g2[m] = b_f[j];
    }
#pragma unroll 2
    for (int k = 0; k < HD; ++k) {
        float wi = W_iou[k * 3 * HD + j];
        float wo = W_iou[k * 3 * HD + HD + j];
        float wu = W_iou[k * 3 * HD + 2 * HD + j];
        float ui = U_iou[k * 3 * HD + j];
        float uo = U_iou[k * 3 * HD + HD + j];
        float uu = U_iou[k * 3 * HD + 2 * HD + j];
        float wf = W_f[k * HD + j];
        float uf = U_f[k * HD + j];
#pragma unroll
        for (int m = 0; m < MT; ++m) {
            float x = X[m][k]; float h1 = H1[m][k]; float h2 = H2[m][k]; float hs = h1 + h2;
            ai[m] = fmaf(x, wi, fmaf(hs, ui, ai[m]));
            ao[m] = fmaf(x, wo, fmaf(hs, uo, ao[m]));
            au[m] = fmaf(x, wu, fmaf(hs, uu, au[m]));
            g1[m] = fmaf(x, wf, fmaf(h1, uf, g1[m]));
            g2[m] = fmaf(x, wf, fmaf(h2, uf, g2[m]));
        }
    }
#pragma unroll
    for (int m = 0; m < MT; ++m) {
        int n = base + m0 + m;
        float iv = sigm(ai[m]); float ov = sigm(ao[m]); float uv = tanh_f(au[m]);
        float f1 = sigm(g1[m]); float f2 = sigm(g2[m]);
        float c1 = cbuf[(size_t)(2 * n + 1) * HD + j];
        float c2 = cbuf[(size_t)(2 * n + 2) * HD + j];
        float cn = fmaf(iv, uv, fmaf(f1, c1, f2 * c2));
        cbuf[(size_t)n * HD + j] = cn;
        hbuf[(size_t)n * HD + j] = ov * tanh_f(cn);
    }
}

extern "C" void kernel_launch(void* const* d_in, const int* in_sizes, int n_in,
                              void* d_out, int out_size, void* d_ws, size_t ws_size,
                              hipStream_t stream)
{
    const int*   feat  = (const int*)d_in[0];
    const float* emb   = (const float*)d_in[4];
    const float* W_iou = (const float*)d_in[5];
    const float* b_iou = (const float*)d_in[6];
    const float* U_iou = (const float*)d_in[7];
    const float* W_f   = (const float*)d_in[8];
    const float* b_f   = (const float*)d_in[9];
    const float* U_f   = (const float*)d_in[10];

    float* hbuf = (float*)d_out;
    float* cbuf = hbuf + (size_t)NN * HD;

    const size_t PACK_BYTES = 2u * 65536u * 2u;                 // 256 KB (WT2+UT2)
    const size_t XP_BYTES   = (size_t)N_INTERNAL * 512 * 4;     // ~134 MB
    if (ws_size >= PACK_BYTES + XP_BYTES) {
        unsigned short* wpk = (unsigned short*)d_ws;
        const unsigned short* WT2 = wpk;
        const unsigned short* UT2 = wpk + 65536;
        float* XP = (float*)((char*)d_ws + PACK_BYTES);

        build_packed<<<64, 256, 0, stream>>>(W_iou, U_iou, W_f, U_f, wpk);
        xp_leaf_kernel<<<2048, 512, 0, stream>>>(feat, emb, WT2, b_iou, b_f, XP, hbuf, cbuf);

        for (int lvl = 1; lvl <= 16; ++lvl) {
            const int count = 1 << (16 - lvl);
            const int base  = count - 1;
            level_u_kernel<<<(count + 63) / 64, 512, 0, stream>>>(
                UT2, XP, hbuf, cbuf, base, count);
        }
    } else {
        // fallback: scalar path (correct, slower)
        leaf_kernel<16><<<65536 / 16, 128, 0, stream>>>(feat, emb, W_iou, b_iou, hbuf, cbuf, 65535);
        for (int lvl = 1; lvl <= 16; ++lvl) {
            const int d = 16 - lvl;
            const int count = 1 << d;
            const int base = count - 1;
            if (count >= 16) {
                level_kernel<16><<<count / 16, 128, 0, stream>>>(
                    feat, emb, W_iou, b_iou, U_iou, W_f, b_f, U_f, hbuf, cbuf, base);
            } else if (count == 8) {
                level_kernel<8><<<1, 128, 0, stream>>>(
                    feat, emb, W_iou, b_iou, U_iou, W_f, b_f, U_f, hbuf, cbuf, base);
            } else if (count == 4) {
                level_kernel<4><<<1, 128, 0, stream>>>(
                    feat, emb, W_iou, b_iou, U_iou, W_f, b_f, U_f, hbuf, cbuf, base);
            } else if (count == 2) {
                level_kernel<2><<<1, 128, 0, stream>>>(
                    feat, emb, W_iou, b_iou, U_iou, W_f, b_f, U_f, hbuf, cbuf, base);
            } else {
                level_kernel<1><<<1, 128, 0, stream>>>(
                    feat, emb, W_iou, b_iou, U_iou, W_f, b_f, U_f, hbuf, cbuf, base);
            }
        }
    }
}

// Round 6
// 315.643 us; speedup vs baseline: 3.7412x; 1.1526x over previous
//
#include <hip/hip_runtime.h>
#include <math.h>

#define NN 131071
#define HD 128
#define N_INTERNAL 65535
#define LEAF_BASE 65535

typedef short bf16x8 __attribute__((ext_vector_type(8)));
typedef unsigned short u16x8 __attribute__((ext_vector_type(8)));
typedef unsigned short u16x4 __attribute__((ext_vector_type(4)));
typedef float f32x4 __attribute__((ext_vector_type(4)));

__device__ __forceinline__ float sigm(float z) { return 1.0f / (1.0f + __expf(-z)); }
__device__ __forceinline__ float tanh_f(float z) { return 1.0f - 2.0f / (__expf(2.0f * z) + 1.0f); }

__device__ __forceinline__ unsigned short f2bf(float f) {
    unsigned u = __float_as_uint(f);
    u += 0x7FFFu + ((u >> 16) & 1u);
    return (unsigned short)(u >> 16);
}
__device__ __forceinline__ float bf2f(unsigned short b) {
    return __uint_as_float(((unsigned)b) << 16);
}

__device__ __forceinline__ f32x4 mfma16(bf16x8 a, bf16x8 b, f32x4 c) {
    return __builtin_amdgcn_mfma_f32_16x16x32_bf16(a, b, c, 0, 0, 0);
}

__device__ __forceinline__ float4 addf4(float4 a, float4 b) {
    float4 r; r.x = a.x + b.x; r.y = a.y + b.y; r.z = a.z + b.z; r.w = a.w + b.w; return r;
}

// store 8 f32 (two float4) as bf16 chunk cc (16B) of row r, XOR-swizzled
__device__ __forceinline__ void lds_store8(unsigned short* region, int r, int cc, float4 a, float4 b) {
    u16x8 p;
    p[0] = f2bf(a.x); p[1] = f2bf(a.y); p[2] = f2bf(a.z); p[3] = f2bf(a.w);
    p[4] = f2bf(b.x); p[5] = f2bf(b.y); p[6] = f2bf(b.z); p[7] = f2bf(b.w);
    *(u16x8*)&region[r * HD + ((cc ^ (r & 7)) << 3)] = p;
}

// A-fragment: row, k-step ks, k-lane kl (16B), swizzled
__device__ __forceinline__ bf16x8 lds_frag(const unsigned short* region, int row, int ks, int kl) {
    int cc = ks * 4 + kl;
    return *(const bf16x8*)&region[row * HD + ((cc ^ (row & 7)) << 3)];
}

// B-fragment from fragment-order-packed weights: contiguous 16B per lane
__device__ __forceinline__ bf16x8 frag2(const unsigned short* M, int ct, int ks, int lane) {
    return *(const bf16x8*)&M[(((ct * 4 + ks) * 64) + lane) * 8];
}

// ---- pack bf16 weights in MFMA-fragment order.
// WT2 (matrix 0): cols 0:384 = W_iou, 384:512 = W_f.  UT2 (matrix 1): U_iou | U_f.
__global__ __launch_bounds__(256) void build_packed(
    const float* __restrict__ W_iou, const float* __restrict__ U_iou,
    const float* __restrict__ W_f, const float* __restrict__ U_f,
    unsigned short* __restrict__ ws)
{
    int f = blockIdx.x * 256 + threadIdx.x;   // 0..16383
    int mat = f >> 13;
    int rem = f & 8191;
    int ct = rem >> 8;
    int ks = (rem >> 6) & 3;
    int lane = rem & 63;
    int col = ct * 16 + (lane & 15);
    int k0 = ks * 32 + (lane >> 4) * 8;
    u16x8 out;
#pragma unroll
    for (int e = 0; e < 8; ++e) {
        int k = k0 + e;
        float v;
        if (mat == 0) v = (col < 384) ? W_iou[k * 384 + col] : W_f[k * HD + (col - 384)];
        else          v = (col < 384) ? U_iou[k * 384 + col] : U_f[k * HD + (col - 384)];
        out[e] = f2bf(v);
    }
    *(u16x8*)&ws[(size_t)f * 8] = out;
}

// ---- XP precompute (packed bf16 u16x4 per (n,j)) + fused leaf gate math.
__global__ __launch_bounds__(512) void xp_leaf_kernel(
    const int* __restrict__ feat, const float* __restrict__ emb,
    const unsigned short* __restrict__ WT2,
    const float* __restrict__ b_iou, const float* __restrict__ b_f,
    unsigned short* __restrict__ XPb, float* __restrict__ hbuf, float* __restrict__ cbuf)
{
    __shared__ unsigned short ldsx[64 * HD];
    const int t = threadIdx.x;
    const int m0 = blockIdx.x * 64;
    {
        int r = t >> 3, c8 = t & 7;
        int n = m0 + r;
        int nn = n < NN ? n : 0;
        const float* sx = emb + (size_t)feat[nn] * HD + c8 * 16;
        float4 x0 = *(const float4*)(sx + 0);
        float4 x1 = *(const float4*)(sx + 4);
        float4 x2 = *(const float4*)(sx + 8);
        float4 x3 = *(const float4*)(sx + 12);
        lds_store8(ldsx, r, c8 * 2 + 0, x0, x1);
        lds_store8(ldsx, r, c8 * 2 + 1, x2, x3);
    }
    __syncthreads();

    const int lane = t & 63, w = t >> 6;
    const int jq = w & 3, mh = w >> 2;
    const int l15 = lane & 15, kl = lane >> 4;

    f32x4 zero = {0.f, 0.f, 0.f, 0.f};
    f32x4 acc[4][2][2];   // [gate i,o,u,f][m-tile][jt]
#pragma unroll
    for (int g = 0; g < 4; ++g)
#pragma unroll
        for (int mp = 0; mp < 2; ++mp)
#pragma unroll
            for (int jt = 0; jt < 2; ++jt) acc[g][mp][jt] = zero;

#pragma unroll
    for (int ks = 0; ks < 4; ++ks) {
        bf16x8 a0 = lds_frag(ldsx, (mh * 2 + 0) * 16 + l15, ks, kl);
        bf16x8 a1 = lds_frag(ldsx, (mh * 2 + 1) * 16 + l15, ks, kl);
#pragma unroll
        for (int g = 0; g < 4; ++g) {
#pragma unroll
            for (int jt = 0; jt < 2; ++jt) {
                bf16x8 b = frag2(WT2, g * 8 + jq * 2 + jt, ks, lane);
                acc[g][0][jt] = mfma16(a0, b, acc[g][0][jt]);
                acc[g][1][jt] = mfma16(a1, b, acc[g][1][jt]);
            }
        }
    }

#pragma unroll
    for (int mp = 0; mp < 2; ++mp) {
#pragma unroll
        for (int jt = 0; jt < 2; ++jt) {
            int j = jq * 32 + jt * 16 + l15;
            int nb = m0 + (mh * 2 + mp) * 16 + kl * 4;
            float bi = b_iou[j], bo = b_iou[HD + j], bu = b_iou[2 * HD + j], bf = b_f[j];
#pragma unroll
            for (int r = 0; r < 4; ++r) {
                int n = nb + r;
                if (n >= NN) continue;
                if (n >= LEAF_BASE) {
                    float iv = sigm(acc[0][mp][jt][r] + bi);
                    float ov = sigm(acc[1][mp][jt][r] + bo);
                    float uv = tanh_f(acc[2][mp][jt][r] + bu);
                    float cv = iv * uv;
                    cbuf[(size_t)n * HD + j] = cv;
                    hbuf[(size_t)n * HD + j] = ov * tanh_f(cv);
                } else {
                    u16x4 pk;
                    pk[0] = f2bf(acc[0][mp][jt][r] + bi);
                    pk[1] = f2bf(acc[1][mp][jt][r] + bo);
                    pk[2] = f2bf(acc[2][mp][jt][r] + bu);
                    pk[3] = f2bf(acc[3][mp][jt][r] + bf);
                    *(u16x4*)&XPb[((size_t)n * HD + j) * 4] = pk;
                }
            }
        }
    }
}

// ---- internal level body: U-projections + gates, fused. 64 nodes per pass.
__device__ __forceinline__ void level_body(
    unsigned short* lds,
    const unsigned short* __restrict__ UT2, const unsigned short* __restrict__ XPb,
    float* __restrict__ hbuf, float* __restrict__ cbuf, int base, int count, int m0)
{
    unsigned short* ldshs = lds;
    unsigned short* ldsh1 = lds + 8192;
    unsigned short* ldsh2 = lds + 16384;

    const int t = threadIdx.x;
    {
        int r = t >> 3, c8 = t & 7;
        int row = m0 + r;
        int n = base + (row < count ? row : 0);
        const float* s1 = hbuf + (size_t)(2 * n + 1) * HD + c8 * 16;
        const float* s2 = hbuf + (size_t)(2 * n + 2) * HD + c8 * 16;
        float4 p0 = *(const float4*)(s1 + 0);
        float4 p1 = *(const float4*)(s1 + 4);
        float4 p2 = *(const float4*)(s1 + 8);
        float4 p3 = *(const float4*)(s1 + 12);
        float4 q0 = *(const float4*)(s2 + 0);
        float4 q1 = *(const float4*)(s2 + 4);
        float4 q2 = *(const float4*)(s2 + 8);
        float4 q3 = *(const float4*)(s2 + 12);
        lds_store8(ldsh1, r, c8 * 2 + 0, p0, p1);
        lds_store8(ldsh1, r, c8 * 2 + 1, p2, p3);
        lds_store8(ldsh2, r, c8 * 2 + 0, q0, q1);
        lds_store8(ldsh2, r, c8 * 2 + 1, q2, q3);
        lds_store8(ldshs, r, c8 * 2 + 0, addf4(p0, q0), addf4(p1, q1));
        lds_store8(ldshs, r, c8 * 2 + 1, addf4(p2, q2), addf4(p3, q3));
    }
    __syncthreads();

    const int lane = t & 63, w = t >> 6;
    const int jq = w & 3, mh = w >> 2;
    const int l15 = lane & 15, kl = lane >> 4;

    f32x4 zero = {0.f, 0.f, 0.f, 0.f};
    f32x4 acc[5][2][2];   // i,o,u,f1,f2
#pragma unroll
    for (int g = 0; g < 5; ++g)
#pragma unroll
        for (int mp = 0; mp < 2; ++mp)
#pragma unroll
            for (int jt = 0; jt < 2; ++jt) acc[g][mp][jt] = zero;

#pragma unroll
    for (int ks = 0; ks < 4; ++ks) {
        bf16x8 ahs0 = lds_frag(ldshs, (mh * 2 + 0) * 16 + l15, ks, kl);
        bf16x8 ahs1 = lds_frag(ldshs, (mh * 2 + 1) * 16 + l15, ks, kl);
        bf16x8 ah10 = lds_frag(ldsh1, (mh * 2 + 0) * 16 + l15, ks, kl);
        bf16x8 ah11 = lds_frag(ldsh1, (mh * 2 + 1) * 16 + l15, ks, kl);
        bf16x8 ah20 = lds_frag(ldsh2, (mh * 2 + 0) * 16 + l15, ks, kl);
        bf16x8 ah21 = lds_frag(ldsh2, (mh * 2 + 1) * 16 + l15, ks, kl);
#pragma unroll
        for (int jt = 0; jt < 2; ++jt) {
            bf16x8 Bi = frag2(UT2,  0 + jq * 2 + jt, ks, lane);
            bf16x8 Bo = frag2(UT2,  8 + jq * 2 + jt, ks, lane);
            bf16x8 Bu = frag2(UT2, 16 + jq * 2 + jt, ks, lane);
            bf16x8 Bf = frag2(UT2, 24 + jq * 2 + jt, ks, lane);
            acc[0][0][jt] = mfma16(ahs0, Bi, acc[0][0][jt]);
            acc[0][1][jt] = mfma16(ahs1, Bi, acc[0][1][jt]);
            acc[1][0][jt] = mfma16(ahs0, Bo, acc[1][0][jt]);
            acc[1][1][jt] = mfma16(ahs1, Bo, acc[1][1][jt]);
            acc[2][0][jt] = mfma16(ahs0, Bu, acc[2][0][jt]);
            acc[2][1][jt] = mfma16(ahs1, Bu, acc[2][1][jt]);
            acc[3][0][jt] = mfma16(ah10, Bf, acc[3][0][jt]);
            acc[3][1][jt] = mfma16(ah11, Bf, acc[3][1][jt]);
            acc[4][0][jt] = mfma16(ah20, Bf, acc[4][0][jt]);
            acc[4][1][jt] = mfma16(ah21, Bf, acc[4][1][jt]);
        }
    }

#pragma unroll
    for (int mp = 0; mp < 2; ++mp) {
#pragma unroll
        for (int jt = 0; jt < 2; ++jt) {
            int j = jq * 32 + jt * 16 + l15;
#pragma unroll
            for (int r = 0; r < 4; ++r) {
                int row = m0 + (mh * 2 + mp) * 16 + kl * 4 + r;
                if (row >= count) continue;
                int n = base + row;
                u16x4 pk = *(const u16x4*)&XPb[((size_t)n * HD + j) * 4];
                float iv = sigm(acc[0][mp][jt][r] + bf2f(pk[0]));
                float ov = sigm(acc[1][mp][jt][r] + bf2f(pk[1]));
                float uv = tanh_f(acc[2][mp][jt][r] + bf2f(pk[2]));
                float fx = bf2f(pk[3]);
                float f1 = sigm(acc[3][mp][jt][r] + fx);
                float f2 = sigm(acc[4][mp][jt][r] + fx);
                float c1 = cbuf[(size_t)(2 * n + 1) * HD + j];
                float c2 = cbuf[(size_t)(2 * n + 2) * HD + j];
                float cn = fmaf(iv, uv, fmaf(f1, c1, f2 * c2));
                cbuf[(size_t)n * HD + j] = cn;
                hbuf[(size_t)n * HD + j] = ov * tanh_f(cn);
            }
        }
    }
}

__global__ __launch_bounds__(512) void level_u_kernel(
    const unsigned short* __restrict__ UT2, const unsigned short* __restrict__ XPb,
    float* __restrict__ hbuf, float* __restrict__ cbuf, int base, int count)
{
    __shared__ unsigned short lds[3 * 64 * HD];
    level_body(lds, UT2, XPb, hbuf, cbuf, base, count, blockIdx.x * 64);
}

// ---- fused tail: levels 9..16 (count 128..1), one block, passes separated by fence+sync.
__global__ __launch_bounds__(512) void tail_kernel(
    const unsigned short* __restrict__ UT2, const unsigned short* __restrict__ XPb,
    float* __restrict__ hbuf, float* __restrict__ cbuf)
{
    __shared__ unsigned short lds[3 * 64 * HD];
    for (int lvl = 9; lvl <= 16; ++lvl) {
        const int count = 1 << (16 - lvl);
        const int base = count - 1;
        for (int m0 = 0; m0 < count; m0 += 64) {
            level_body(lds, UT2, XPb, hbuf, cbuf, base, count, m0);
            __threadfence();
            __syncthreads();
        }
    }
}

// ---------------- scalar fallback (known-correct R3 path, used only if ws too small) ----------------
template <int MT>
__global__ __launch_bounds__(128) void leaf_kernel(
    const int* __restrict__ feat, const float* __restrict__ emb,
    const float* __restrict__ W_iou, const float* __restrict__ b_iou,
    float* __restrict__ hbuf, float* __restrict__ cbuf, int base)
{
    __shared__ float X[MT][HD];
    const int j = threadIdx.x;
    const int m0 = blockIdx.x * MT;
#pragma unroll
    for (int m = 0; m < MT; ++m) {
        int n = base + m0 + m;
        X[m][j] = emb[(size_t)feat[n] * HD + j];
    }
    __syncthreads();
    float ai[MT], ao[MT], au[MT];
#pragma unroll
    for (int m = 0; m < MT; ++m) {
        ai[m] = b_iou[j]; ao[m] = b_iou[HD + j]; au[m] = b_iou[2 * HD + j];
    }
#pragma unroll 4
    for (int k = 0; k < HD; ++k) {
        float wi = W_iou[k * 3 * HD + j];
        float wo = W_iou[k * 3 * HD + HD + j];
        float wu = W_iou[k * 3 * HD + 2 * HD + j];
#pragma unroll
        for (int m = 0; m < MT; ++m) {
            float x = X[m][k];
            ai[m] = fmaf(x, wi, ai[m]); ao[m] = fmaf(x, wo, ao[m]); au[m] = fmaf(x, wu, au[m]);
        }
    }
#pragma unroll
    for (int m = 0; m < MT; ++m) {
        int n = base + m0 + m;
        float iv = sigm(ai[m]); float ov = sigm(ao[m]); float uv = tanh_f(au[m]);
        float cv = iv * uv;
        cbuf[(size_t)n * HD + j] = cv;
        hbuf[(size_t)n * HD + j] = ov * tanh_f(cv);
    }
}

template <int MT>
__global__ __launch_bounds__(128) void level_kernel(
    const int* __restrict__ feat, const float* __restrict__ emb,
    const float* __restrict__ W_iou, const float* __restrict__ b_iou,
    const float* __restrict__ U_iou,
    const float* __restrict__ W_f, const float* __restrict__ b_f,
    const float* __restrict__ U_f,
    float* __restrict__ hbuf, float* __restrict__ cbuf, int base)
{
    __shared__ float X[MT][HD];
    __shared__ float H1[MT][HD];
    __shared__ float H2[MT][HD];
    const int j = threadIdx.x;
    const int m0 = blockIdx.x * MT;
#pragma unroll
    for (int m = 0; m < MT; ++m) {
        int n = base + m0 + m;
        X[m][j]  = emb[(size_t)feat[n] * HD + j];
        H1[m][j] = hbuf[(size_t)(2 * n + 1) * HD + j];
        H2[m][j] = hbuf[(size_t)(2 * n + 2) * HD + j];
    }
    __syncthreads();
    float ai[MT], ao[MT], au[MT], g1[MT], g2[MT];
#pragma unroll
    for (int m = 0; m < MT; ++m) {
        ai[m] = b_iou[j]; ao[m] = b_iou[HD + j]; au[m] = b_iou[2 * HD + j];
        g1[m] = b_f[j]; g2[m] = b_f[j];
    }
#pragma unroll 2
    for (int k = 0; k < HD; ++k) {
        float wi = W_iou[k * 3 * HD + j];
        float wo = W_iou[k * 3 * HD + HD + j];
        float wu = W_iou[k * 3 * HD + 2 * HD + j];
        float ui = U_iou[k * 3 * HD + j];
        float uo = U_iou[k * 3 * HD + HD + j];
        float uu = U_iou[k * 3 * HD + 2 * HD + j];
        float wf = W_f[k * HD + j];
        float uf = U_f[k * HD + j];
#pragma unroll
        for (int m = 0; m < MT; ++m) {
            float x = X[m][k]; float h1 = H1[m][k]; float h2 = H2[m][k]; float hs = h1 + h2;
            ai[m] = fmaf(x, wi, fmaf(hs, ui, ai[m]));
            ao[m] = fmaf(x, wo, fmaf(hs, uo, ao[m]));
            au[m] = fmaf(x, wu, fmaf(hs, uu, au[m]));
            g1[m] = fmaf(x, wf, fmaf(h1, uf, g1[m]));
            g2[m] = fmaf(x, wf, fmaf(h2, uf, g2[m]));
        }
    }
#pragma unroll
    for (int m = 0; m < MT; ++m) {
        int n = base + m0 + m;
        float iv = sigm(ai[m]); float ov = sigm(ao[m]); float uv = tanh_f(au[m]);
        float f1 = sigm(g1[m]); float f2 = sigm(g2[m]);
        float c1 = cbuf[(size_t)(2 * n + 1) * HD + j];
        float c2 = cbuf[(size_t)(2 * n + 2) * HD + j];
        float cn = fmaf(iv, uv, fmaf(f1, c1, f2 * c2));
        cbuf[(size_t)n * HD + j] = cn;
        hbuf[(size_t)n * HD + j] = ov * tanh_f(cn);
    }
}

extern "C" void kernel_launch(void* const* d_in, const int* in_sizes, int n_in,
                              void* d_out, int out_size, void* d_ws, size_t ws_size,
                              hipStream_t stream)
{
    const int*   feat  = (const int*)d_in[0];
    const float* emb   = (const float*)d_in[4];
    const float* W_iou = (const float*)d_in[5];
    const float* b_iou = (const float*)d_in[6];
    const float* U_iou = (const float*)d_in[7];
    const float* W_f   = (const float*)d_in[8];
    const float* b_f   = (const float*)d_in[9];
    const float* U_f   = (const float*)d_in[10];

    float* hbuf = (float*)d_out;
    float* cbuf = hbuf + (size_t)NN * HD;

    const size_t PACK_BYTES = 2u * 65536u * 2u;                      // 256 KB (WT2+UT2)
    const size_t XP_BYTES   = (size_t)N_INTERNAL * HD * 4 * 2;       // ~67 MB (bf16 x4 gates)
    if (ws_size >= PACK_BYTES + XP_BYTES) {
        unsigned short* wpk = (unsigned short*)d_ws;
        const unsigned short* WT2 = wpk;
        const unsigned short* UT2 = wpk + 65536;
        unsigned short* XPb = (unsigned short*)((char*)d_ws + PACK_BYTES);

        build_packed<<<64, 256, 0, stream>>>(W_iou, U_iou, W_f, U_f, wpk);
        xp_leaf_kernel<<<2048, 512, 0, stream>>>(feat, emb, WT2, b_iou, b_f, XPb, hbuf, cbuf);

        for (int lvl = 1; lvl <= 8; ++lvl) {
            const int count = 1 << (16 - lvl);
            const int base  = count - 1;
            level_u_kernel<<<count / 64, 512, 0, stream>>>(UT2, XPb, hbuf, cbuf, base, count);
        }
        tail_kernel<<<1, 512, 0, stream>>>(UT2, XPb, hbuf, cbuf);
    } else {
        // fallback: scalar path (correct, slower)
        leaf_kernel<16><<<65536 / 16, 128, 0, stream>>>(feat, emb, W_iou, b_iou, hbuf, cbuf, 65535);
        for (int lvl = 1; lvl <= 16; ++lvl) {
            const int d = 16 - lvl;
            const int count = 1 << d;
            const int base = count - 1;
            if (count >= 16) {
                level_kernel<16><<<count / 16, 128, 0, stream>>>(
                    feat, emb, W_iou, b_iou, U_iou, W_f, b_f, U_f, hbuf, cbuf, base);
            } else if (count == 8) {
                level_kernel<8><<<1, 128, 0, stream>>>(
                    feat, emb, W_iou, b_iou, U_iou, W_f, b_f, U_f, hbuf, cbuf, base);
            } else if (count == 4) {
                level_kernel<4><<<1, 128, 0, stream>>>(
                    feat, emb, W_iou, b_iou, U_iou, W_f, b_f, U_f, hbuf, cbuf, base);
            } else if (count == 2) {
                level_kernel<2><<<1, 128, 0, stream>>>(
                    feat, emb, W_iou, b_iou, U_iou, W_f, b_f, U_f, hbuf, cbuf, base);
            } else {
                level_kernel<1><<<1, 128, 0, stream>>>(
                    feat, emb, W_iou, b_iou, U_iou, W_f, b_f, U_f, hbuf, cbuf, base);
            }
        }
    }
}

// Round 7
// 309.569 us; speedup vs baseline: 3.8146x; 1.0196x over previous
//
#include <hip/hip_runtime.h>
#include <math.h>

#define NN 131071
#define HD 128
#define N_INTERNAL 65535
#define LEAF_BASE 65535

typedef short bf16x8 __attribute__((ext_vector_type(8)));
typedef unsigned short u16x8 __attribute__((ext_vector_type(8)));
typedef unsigned short u16x4 __attribute__((ext_vector_type(4)));
typedef float f32x4 __attribute__((ext_vector_type(4)));

__device__ __forceinline__ float sigm(float z) { return 1.0f / (1.0f + __expf(-z)); }
__device__ __forceinline__ float tanh_f(float z) { return 1.0f - 2.0f / (__expf(2.0f * z) + 1.0f); }

__device__ __forceinline__ unsigned short f2bf(float f) {
    unsigned u = __float_as_uint(f);
    u += 0x7FFFu + ((u >> 16) & 1u);
    return (unsigned short)(u >> 16);
}
__device__ __forceinline__ float bf2f(unsigned short b) {
    return __uint_as_float(((unsigned)b) << 16);
}

__device__ __forceinline__ f32x4 mfma16(bf16x8 a, bf16x8 b, f32x4 c) {
    return __builtin_amdgcn_mfma_f32_16x16x32_bf16(a, b, c, 0, 0, 0);
}

__device__ __forceinline__ float4 addf4(float4 a, float4 b) {
    float4 r; r.x = a.x + b.x; r.y = a.y + b.y; r.z = a.z + b.z; r.w = a.w + b.w; return r;
}

// store 8 f32 (two float4) as bf16 chunk cc (16B) of row r, XOR-swizzled
__device__ __forceinline__ void lds_store8(unsigned short* region, int r, int cc, float4 a, float4 b) {
    u16x8 p;
    p[0] = f2bf(a.x); p[1] = f2bf(a.y); p[2] = f2bf(a.z); p[3] = f2bf(a.w);
    p[4] = f2bf(b.x); p[5] = f2bf(b.y); p[6] = f2bf(b.z); p[7] = f2bf(b.w);
    *(u16x8*)&region[r * HD + ((cc ^ (r & 7)) << 3)] = p;
}

// A-fragment: row, k-step ks, k-lane kl (16B), swizzled
__device__ __forceinline__ bf16x8 lds_frag(const unsigned short* region, int row, int ks, int kl) {
    int cc = ks * 4 + kl;
    return *(const bf16x8*)&region[row * HD + ((cc ^ (row & 7)) << 3)];
}

// B-fragment from fragment-order-packed weights: contiguous 16B per lane
__device__ __forceinline__ bf16x8 frag2(const unsigned short* M, int ct, int ks, int lane) {
    return *(const bf16x8*)&M[(((ct * 4 + ks) * 64) + lane) * 8];
}

// ---- pack bf16 weights in MFMA-fragment order.
// WT2 (matrix 0): cols 0:384 = W_iou, 384:512 = W_f.  UT2 (matrix 1): U_iou | U_f.
__global__ __launch_bounds__(256) void build_packed(
    const float* __restrict__ W_iou, const float* __restrict__ U_iou,
    const float* __restrict__ W_f, const float* __restrict__ U_f,
    unsigned short* __restrict__ ws)
{
    int f = blockIdx.x * 256 + threadIdx.x;   // 0..16383
    int mat = f >> 13;
    int rem = f & 8191;
    int ct = rem >> 8;
    int ks = (rem >> 6) & 3;
    int lane = rem & 63;
    int col = ct * 16 + (lane & 15);
    int k0 = ks * 32 + (lane >> 4) * 8;
    u16x8 out;
#pragma unroll
    for (int e = 0; e < 8; ++e) {
        int k = k0 + e;
        float v;
        if (mat == 0) v = (col < 384) ? W_iou[k * 384 + col] : W_f[k * HD + (col - 384)];
        else          v = (col < 384) ? U_iou[k * 384 + col] : U_f[k * HD + (col - 384)];
        out[e] = f2bf(v);
    }
    *(u16x8*)&ws[(size_t)f * 8] = out;
}

// ---- XP precompute (packed bf16 u16x4 per (n,j)) + fused leaf gate math.
__global__ __launch_bounds__(512) void xp_leaf_kernel(
    const int* __restrict__ feat, const float* __restrict__ emb,
    const unsigned short* __restrict__ WT2,
    const float* __restrict__ b_iou, const float* __restrict__ b_f,
    unsigned short* __restrict__ XPb, float* __restrict__ hbuf, float* __restrict__ cbuf)
{
    __shared__ unsigned short ldsx[64 * HD];
    const int t = threadIdx.x;
    const int m0 = blockIdx.x * 64;
    {
        int r = t >> 3, c8 = t & 7;
        int n = m0 + r;
        int nn = n < NN ? n : 0;
        const float* sx = emb + (size_t)feat[nn] * HD + c8 * 16;
        float4 x0 = *(const float4*)(sx + 0);
        float4 x1 = *(const float4*)(sx + 4);
        float4 x2 = *(const float4*)(sx + 8);
        float4 x3 = *(const float4*)(sx + 12);
        lds_store8(ldsx, r, c8 * 2 + 0, x0, x1);
        lds_store8(ldsx, r, c8 * 2 + 1, x2, x3);
    }
    __syncthreads();

    const int lane = t & 63, w = t >> 6;
    const int jq = w & 3, mh = w >> 2;
    const int l15 = lane & 15, kl = lane >> 4;

    f32x4 zero = {0.f, 0.f, 0.f, 0.f};
    f32x4 acc[4][2][2];   // [gate i,o,u,f][m-tile][jt]
#pragma unroll
    for (int g = 0; g < 4; ++g)
#pragma unroll
        for (int mp = 0; mp < 2; ++mp)
#pragma unroll
            for (int jt = 0; jt < 2; ++jt) acc[g][mp][jt] = zero;

#pragma unroll
    for (int ks = 0; ks < 4; ++ks) {
        bf16x8 a0 = lds_frag(ldsx, (mh * 2 + 0) * 16 + l15, ks, kl);
        bf16x8 a1 = lds_frag(ldsx, (mh * 2 + 1) * 16 + l15, ks, kl);
#pragma unroll
        for (int g = 0; g < 4; ++g) {
#pragma unroll
            for (int jt = 0; jt < 2; ++jt) {
                bf16x8 b = frag2(WT2, g * 8 + jq * 2 + jt, ks, lane);
                acc[g][0][jt] = mfma16(a0, b, acc[g][0][jt]);
                acc[g][1][jt] = mfma16(a1, b, acc[g][1][jt]);
            }
        }
    }

#pragma unroll
    for (int mp = 0; mp < 2; ++mp) {
#pragma unroll
        for (int jt = 0; jt < 2; ++jt) {
            int j = jq * 32 + jt * 16 + l15;
            int nb = m0 + (mh * 2 + mp) * 16 + kl * 4;
            float bi = b_iou[j], bo = b_iou[HD + j], bu = b_iou[2 * HD + j], bf = b_f[j];
#pragma unroll
            for (int r = 0; r < 4; ++r) {
                int n = nb + r;
                if (n >= NN) continue;
                if (n >= LEAF_BASE) {
                    float iv = sigm(acc[0][mp][jt][r] + bi);
                    float ov = sigm(acc[1][mp][jt][r] + bo);
                    float uv = tanh_f(acc[2][mp][jt][r] + bu);
                    float cv = iv * uv;
                    cbuf[(size_t)n * HD + j] = cv;
                    hbuf[(size_t)n * HD + j] = ov * tanh_f(cv);
                } else {
                    u16x4 pk;
                    pk[0] = f2bf(acc[0][mp][jt][r] + bi);
                    pk[1] = f2bf(acc[1][mp][jt][r] + bo);
                    pk[2] = f2bf(acc[2][mp][jt][r] + bu);
                    pk[3] = f2bf(acc[3][mp][jt][r] + bf);
                    *(u16x4*)&XPb[((size_t)n * HD + j) * 4] = pk;
                }
            }
        }
    }
}

// ---- internal level body: U-projections + gates, fused. 64 nodes per pass.
__device__ __forceinline__ void level_body(
    unsigned short* lds,
    const unsigned short* __restrict__ UT2, const unsigned short* __restrict__ XPb,
    float* __restrict__ hbuf, float* __restrict__ cbuf, int base, int count, int m0)
{
    unsigned short* ldshs = lds;
    unsigned short* ldsh1 = lds + 8192;
    unsigned short* ldsh2 = lds + 16384;

    const int t = threadIdx.x;
    {
        int r = t >> 3, c8 = t & 7;
        int row = m0 + r;
        int n = base + (row < count ? row : 0);
        const float* s1 = hbuf + (size_t)(2 * n + 1) * HD + c8 * 16;
        const float* s2 = hbuf + (size_t)(2 * n + 2) * HD + c8 * 16;
        float4 p0 = *(const float4*)(s1 + 0);
        float4 p1 = *(const float4*)(s1 + 4);
        float4 p2 = *(const float4*)(s1 + 8);
        float4 p3 = *(const float4*)(s1 + 12);
        float4 q0 = *(const float4*)(s2 + 0);
        float4 q1 = *(const float4*)(s2 + 4);
        float4 q2 = *(const float4*)(s2 + 8);
        float4 q3 = *(const float4*)(s2 + 12);
        lds_store8(ldsh1, r, c8 * 2 + 0, p0, p1);
        lds_store8(ldsh1, r, c8 * 2 + 1, p2, p3);
        lds_store8(ldsh2, r, c8 * 2 + 0, q0, q1);
        lds_store8(ldsh2, r, c8 * 2 + 1, q2, q3);
        lds_store8(ldshs, r, c8 * 2 + 0, addf4(p0, q0), addf4(p1, q1));
        lds_store8(ldshs, r, c8 * 2 + 1, addf4(p2, q2), addf4(p3, q3));
    }
    __syncthreads();

    const int lane = t & 63, w = t >> 6;
    const int jq = w & 3, mh = w >> 2;
    const int l15 = lane & 15, kl = lane >> 4;

    f32x4 zero = {0.f, 0.f, 0.f, 0.f};
    f32x4 acc[5][2][2];   // i,o,u,f1,f2
#pragma unroll
    for (int g = 0; g < 5; ++g)
#pragma unroll
        for (int mp = 0; mp < 2; ++mp)
#pragma unroll
            for (int jt = 0; jt < 2; ++jt) acc[g][mp][jt] = zero;

#pragma unroll
    for (int ks = 0; ks < 4; ++ks) {
        bf16x8 ahs0 = lds_frag(ldshs, (mh * 2 + 0) * 16 + l15, ks, kl);
        bf16x8 ahs1 = lds_frag(ldshs, (mh * 2 + 1) * 16 + l15, ks, kl);
        bf16x8 ah10 = lds_frag(ldsh1, (mh * 2 + 0) * 16 + l15, ks, kl);
        bf16x8 ah11 = lds_frag(ldsh1, (mh * 2 + 1) * 16 + l15, ks, kl);
        bf16x8 ah20 = lds_frag(ldsh2, (mh * 2 + 0) * 16 + l15, ks, kl);
        bf16x8 ah21 = lds_frag(ldsh2, (mh * 2 + 1) * 16 + l15, ks, kl);
#pragma unroll
        for (int jt = 0; jt < 2; ++jt) {
            bf16x8 Bi = frag2(UT2,  0 + jq * 2 + jt, ks, lane);
            bf16x8 Bo = frag2(UT2,  8 + jq * 2 + jt, ks, lane);
            bf16x8 Bu = frag2(UT2, 16 + jq * 2 + jt, ks, lane);
            bf16x8 Bf = frag2(UT2, 24 + jq * 2 + jt, ks, lane);
            acc[0][0][jt] = mfma16(ahs0, Bi, acc[0][0][jt]);
            acc[0][1][jt] = mfma16(ahs1, Bi, acc[0][1][jt]);
            acc[1][0][jt] = mfma16(ahs0, Bo, acc[1][0][jt]);
            acc[1][1][jt] = mfma16(ahs1, Bo, acc[1][1][jt]);
            acc[2][0][jt] = mfma16(ahs0, Bu, acc[2][0][jt]);
            acc[2][1][jt] = mfma16(ahs1, Bu, acc[2][1][jt]);
            acc[3][0][jt] = mfma16(ah10, Bf, acc[3][0][jt]);
            acc[3][1][jt] = mfma16(ah11, Bf, acc[3][1][jt]);
            acc[4][0][jt] = mfma16(ah20, Bf, acc[4][0][jt]);
            acc[4][1][jt] = mfma16(ah21, Bf, acc[4][1][jt]);
        }
    }

#pragma unroll
    for (int mp = 0; mp < 2; ++mp) {
#pragma unroll
        for (int jt = 0; jt < 2; ++jt) {
            int j = jq * 32 + jt * 16 + l15;
#pragma unroll
            for (int r = 0; r < 4; ++r) {
                int row = m0 + (mh * 2 + mp) * 16 + kl * 4 + r;
                if (row >= count) continue;
                int n = base + row;
                u16x4 pk = *(const u16x4*)&XPb[((size_t)n * HD + j) * 4];
                float iv = sigm(acc[0][mp][jt][r] + bf2f(pk[0]));
                float ov = sigm(acc[1][mp][jt][r] + bf2f(pk[1]));
                float uv = tanh_f(acc[2][mp][jt][r] + bf2f(pk[2]));
                float fx = bf2f(pk[3]);
                float f1 = sigm(acc[3][mp][jt][r] + fx);
                float f2 = sigm(acc[4][mp][jt][r] + fx);
                float c1 = cbuf[(size_t)(2 * n + 1) * HD + j];
                float c2 = cbuf[(size_t)(2 * n + 2) * HD + j];
                float cn = fmaf(iv, uv, fmaf(f1, c1, f2 * c2));
                cbuf[(size_t)n * HD + j] = cn;
                hbuf[(size_t)n * HD + j] = ov * tanh_f(cn);
            }
        }
    }
}

__global__ __launch_bounds__(512) void level_u_kernel(
    const unsigned short* __restrict__ UT2, const unsigned short* __restrict__ XPb,
    float* __restrict__ hbuf, float* __restrict__ cbuf, int base, int count)
{
    __shared__ unsigned short lds[3 * 64 * HD];
    level_body(lds, UT2, XPb, hbuf, cbuf, base, count, blockIdx.x * 64);
}

// ---- fused tail: levels 9..16 (count 128..1), ONE workgroup.
// No __threadfence(): single workgroup on a single CU — __syncthreads()'s
// workgroup-scope acquire/release (s_waitcnt before s_barrier) is sufficient
// for pass-to-pass global r/w ordering. Device-scope fence costs ~10us/call
// on CDNA4 (per-XCD L2 writeback) and was 96us of the R6 profile.
__global__ __launch_bounds__(512) void tail_kernel(
    const unsigned short* __restrict__ UT2, const unsigned short* __restrict__ XPb,
    float* __restrict__ hbuf, float* __restrict__ cbuf)
{
    __shared__ unsigned short lds[3 * 64 * HD];
    for (int lvl = 9; lvl <= 16; ++lvl) {
        const int count = 1 << (16 - lvl);
        const int base = count - 1;
        for (int m0 = 0; m0 < count; m0 += 64) {
            level_body(lds, UT2, XPb, hbuf, cbuf, base, count, m0);
            __syncthreads();
        }
    }
}

// ---------------- scalar fallback (known-correct R3 path, used only if ws too small) ----------------
template <int MT>
__global__ __launch_bounds__(128) void leaf_kernel(
    const int* __restrict__ feat, const float* __restrict__ emb,
    const float* __restrict__ W_iou, const float* __restrict__ b_iou,
    float* __restrict__ hbuf, float* __restrict__ cbuf, int base)
{
    __shared__ float X[MT][HD];
    const int j = threadIdx.x;
    const int m0 = blockIdx.x * MT;
#pragma unroll
    for (int m = 0; m < MT; ++m) {
        int n = base + m0 + m;
        X[m][j] = emb[(size_t)feat[n] * HD + j];
    }
    __syncthreads();
    float ai[MT], ao[MT], au[MT];
#pragma unroll
    for (int m = 0; m < MT; ++m) {
        ai[m] = b_iou[j]; ao[m] = b_iou[HD + j]; au[m] = b_iou[2 * HD + j];
    }
#pragma unroll 4
    for (int k = 0; k < HD; ++k) {
        float wi = W_iou[k * 3 * HD + j];
        float wo = W_iou[k * 3 * HD + HD + j];
        float wu = W_iou[k * 3 * HD + 2 * HD + j];
#pragma unroll
        for (int m = 0; m < MT; ++m) {
            float x = X[m][k];
            ai[m] = fmaf(x, wi, ai[m]); ao[m] = fmaf(x, wo, ao[m]); au[m] = fmaf(x, wu, au[m]);
        }
    }
#pragma unroll
    for (int m = 0; m < MT; ++m) {
        int n = base + m0 + m;
        float iv = sigm(ai[m]); float ov = sigm(ao[m]); float uv = tanh_f(au[m]);
        float cv = iv * uv;
        cbuf[(size_t)n * HD + j] = cv;
        hbuf[(size_t)n * HD + j] = ov * tanh_f(cv);
    }
}

template <int MT>
__global__ __launch_bounds__(128) void level_kernel(
    const int* __restrict__ feat, const float* __restrict__ emb,
    const float* __restrict__ W_iou, const float* __restrict__ b_iou,
    const float* __restrict__ U_iou,
    const float* __restrict__ W_f, const float* __restrict__ b_f,
    const float* __restrict__ U_f,
    float* __restrict__ hbuf, float* __restrict__ cbuf, int base)
{
    __shared__ float X[MT][HD];
    __shared__ float H1[MT][HD];
    __shared__ float H2[MT][HD];
    const int j = threadIdx.x;
    const int m0 = blockIdx.x * MT;
#pragma unroll
    for (int m = 0; m < MT; ++m) {
        int n = base + m0 + m;
        X[m][j]  = emb[(size_t)feat[n] * HD + j];
        H1[m][j] = hbuf[(size_t)(2 * n + 1) * HD + j];
        H2[m][j] = hbuf[(size_t)(2 * n + 2) * HD + j];
    }
    __syncthreads();
    float ai[MT], ao[MT], au[MT], g1[MT], g2[MT];
#pragma unroll
    for (int m = 0; m < MT; ++m) {
        ai[m] = b_iou[j]; ao[m] = b_iou[HD + j]; au[m] = b_iou[2 * HD + j];
        g1[m] = b_f[j]; g2[m] = b_f[j];
    }
#pragma unroll 2
    for (int k = 0; k < HD; ++k) {
        float wi = W_iou[k * 3 * HD + j];
        float wo = W_iou[k * 3 * HD + HD + j];
        float wu = W_iou[k * 3 * HD + 2 * HD + j];
        float ui = U_iou[k * 3 * HD + j];
        float uo = U_iou[k * 3 * HD + HD + j];
        float uu = U_iou[k * 3 * HD + 2 * HD + j];
        float wf = W_f[k * HD + j];
        float uf = U_f[k * HD + j];
#pragma unroll
        for (int m = 0; m < MT; ++m) {
            float x = X[m][k]; float h1 = H1[m][k]; float h2 = H2[m][k]; float hs = h1 + h2;
            ai[m] = fmaf(x, wi, fmaf(hs, ui, ai[m]));
            ao[m] = fmaf(x, wo, fmaf(hs, uo, ao[m]));
            au[m] = fmaf(x, wu, fmaf(hs, uu, au[m]));
            g1[m] = fmaf(x, wf, fmaf(h1, uf, g1[m]));
            g2[m] = fmaf(x, wf, fmaf(h2, uf, g2[m]));
        }
    }
#pragma unroll
    for (int m = 0; m < MT; ++m) {
        int n = base + m0 + m;
        float iv = sigm(ai[m]); float ov = sigm(ao[m]); float uv = tanh_f(au[m]);
        float f1 = sigm(g1[m]); float f2 = sigm(g2[m]);
        float c1 = cbuf[(size_t)(2 * n + 1) * HD + j];
        float c2 = cbuf[(size_t)(2 * n + 2) * HD + j];
        float cn = fmaf(iv, uv, fmaf(f1, c1, f2 * c2));
        cbuf[(size_t)n * HD + j] = cn;
        hbuf[(size_t)n * HD + j] = ov * tanh_f(cn);
    }
}

extern "C" void kernel_launch(void* const* d_in, const int* in_sizes, int n_in,
                              void* d_out, int out_size, void* d_ws, size_t ws_size,
                              hipStream_t stream)
{
    const int*   feat  = (const int*)d_in[0];
    const float* emb   = (const float*)d_in[4];
    const float* W_iou = (const float*)d_in[5];
    const float* b_iou = (const float*)d_in[6];
    const float* U_iou = (const float*)d_in[7];
    const float* W_f   = (const float*)d_in[8];
    const float* b_f   = (const float*)d_in[9];
    const float* U_f   = (const float*)d_in[10];

    float* hbuf = (float*)d_out;
    float* cbuf = hbuf + (size_t)NN * HD;

    const size_t PACK_BYTES = 2u * 65536u * 2u;                      // 256 KB (WT2+UT2)
    const size_t XP_BYTES   = (size_t)N_INTERNAL * HD * 4 * 2;       // ~67 MB (bf16 x4 gates)
    if (ws_size >= PACK_BYTES + XP_BYTES) {
        unsigned short* wpk = (unsigned short*)d_ws;
        const unsigned short* WT2 = wpk;
        const unsigned short* UT2 = wpk + 65536;
        unsigned short* XPb = (unsigned short*)((char*)d_ws + PACK_BYTES);

        build_packed<<<64, 256, 0, stream>>>(W_iou, U_iou, W_f, U_f, wpk);
        xp_leaf_kernel<<<2048, 512, 0, stream>>>(feat, emb, WT2, b_iou, b_f, XPb, hbuf, cbuf);

        for (int lvl = 1; lvl <= 8; ++lvl) {
            const int count = 1 << (16 - lvl);
            const int base  = count - 1;
            level_u_kernel<<<count / 64, 512, 0, stream>>>(UT2, XPb, hbuf, cbuf, base, count);
        }
        tail_kernel<<<1, 512, 0, stream>>>(UT2, XPb, hbuf, cbuf);
    } else {
        // fallback: scalar path (correct, slower)
        leaf_kernel<16><<<65536 / 16, 128, 0, stream>>>(feat, emb, W_iou, b_iou, hbuf, cbuf, 65535);
        for (int lvl = 1; lvl <= 16; ++lvl) {
            const int d = 16 - lvl;
            const int count = 1 << d;
            const int base = count - 1;
            if (count >= 16) {
                level_kernel<16><<<count / 16, 128, 0, stream>>>(
                    feat, emb, W_iou, b_iou, U_iou, W_f, b_f, U_f, hbuf, cbuf, base);
            } else if (count == 8) {
                level_kernel<8><<<1, 128, 0, stream>>>(
                    feat, emb, W_iou, b_iou, U_iou, W_f, b_f, U_f, hbuf, cbuf, base);
            } else if (count == 4) {
                level_kernel<4><<<1, 128, 0, stream>>>(
                    feat, emb, W_iou, b_iou, U_iou, W_f, b_f, U_f, hbuf, cbuf, base);
            } else if (count == 2) {
                level_kernel<2><<<1, 128, 0, stream>>>(
                    feat, emb, W_iou, b_iou, U_iou, W_f, b_f, U_f, hbuf, cbuf, base);
            } else {
                level_kernel<1><<<1, 128, 0, stream>>>(
                    feat, emb, W_iou, b_iou, U_iou, W_f, b_f, U_f, hbuf, cbuf, base);
            }
        }
    }
}

// Round 8
// 308.768 us; speedup vs baseline: 3.8245x; 1.0026x over previous
//
#include <hip/hip_runtime.h>
#include <math.h>

#define NN 131071
#define HD 128
#define N_INTERNAL 65535
#define LEAF_BASE 65535

typedef short bf16x8 __attribute__((ext_vector_type(8)));
typedef unsigned short u16x8 __attribute__((ext_vector_type(8)));
typedef unsigned short u16x4 __attribute__((ext_vector_type(4)));
typedef float f32x4 __attribute__((ext_vector_type(4)));

__device__ __forceinline__ float sigm(float z) { return 1.0f / (1.0f + __expf(-z)); }
__device__ __forceinline__ float tanh_f(float z) { return 1.0f - 2.0f / (__expf(2.0f * z) + 1.0f); }

__device__ __forceinline__ unsigned short f2bf(float f) {
    unsigned u = __float_as_uint(f);
    u += 0x7FFFu + ((u >> 16) & 1u);
    return (unsigned short)(u >> 16);
}
__device__ __forceinline__ float bf2f(unsigned short b) {
    return __uint_as_float(((unsigned)b) << 16);
}

__device__ __forceinline__ f32x4 mfma16(bf16x8 a, bf16x8 b, f32x4 c) {
    return __builtin_amdgcn_mfma_f32_16x16x32_bf16(a, b, c, 0, 0, 0);
}

__device__ __forceinline__ float4 addf4(float4 a, float4 b) {
    float4 r; r.x = a.x + b.x; r.y = a.y + b.y; r.z = a.z + b.z; r.w = a.w + b.w; return r;
}

// pack two float4 into a bf16x8 fragment (round-to-nearest-even)
__device__ __forceinline__ bf16x8 pk8(float4 a, float4 b) {
    u16x8 p;
    p[0] = f2bf(a.x); p[1] = f2bf(a.y); p[2] = f2bf(a.z); p[3] = f2bf(a.w);
    p[4] = f2bf(b.x); p[5] = f2bf(b.y); p[6] = f2bf(b.z); p[7] = f2bf(b.w);
    return *(bf16x8*)&p;
}

// store 8 f32 (two float4) as bf16 chunk cc (16B) of row r, XOR-swizzled
__device__ __forceinline__ void lds_store8(unsigned short* region, int r, int cc, float4 a, float4 b) {
    u16x8 p;
    p[0] = f2bf(a.x); p[1] = f2bf(a.y); p[2] = f2bf(a.z); p[3] = f2bf(a.w);
    p[4] = f2bf(b.x); p[5] = f2bf(b.y); p[6] = f2bf(b.z); p[7] = f2bf(b.w);
    *(u16x8*)&region[r * HD + ((cc ^ (r & 7)) << 3)] = p;
}

// A-fragment: row, k-step ks, k-lane kl (16B), swizzled
__device__ __forceinline__ bf16x8 lds_frag(const unsigned short* region, int row, int ks, int kl) {
    int cc = ks * 4 + kl;
    return *(const bf16x8*)&region[row * HD + ((cc ^ (row & 7)) << 3)];
}

// B-fragment from fragment-order-packed weights: contiguous 16B per lane
__device__ __forceinline__ bf16x8 frag2(const unsigned short* M, int ct, int ks, int lane) {
    return *(const bf16x8*)&M[(((ct * 4 + ks) * 64) + lane) * 8];
}

// ---- pack bf16 weights in MFMA-fragment order.
// WT2 (matrix 0): cols 0:384 = W_iou, 384:512 = W_f.  UT2 (matrix 1): U_iou | U_f.
__global__ __launch_bounds__(256) void build_packed(
    const float* __restrict__ W_iou, const float* __restrict__ U_iou,
    const float* __restrict__ W_f, const float* __restrict__ U_f,
    unsigned short* __restrict__ ws)
{
    int f = blockIdx.x * 256 + threadIdx.x;   // 0..16383
    int mat = f >> 13;
    int rem = f & 8191;
    int ct = rem >> 8;
    int ks = (rem >> 6) & 3;
    int lane = rem & 63;
    int col = ct * 16 + (lane & 15);
    int k0 = ks * 32 + (lane >> 4) * 8;
    u16x8 out;
#pragma unroll
    for (int e = 0; e < 8; ++e) {
        int k = k0 + e;
        float v;
        if (mat == 0) v = (col < 384) ? W_iou[k * 384 + col] : W_f[k * HD + (col - 384)];
        else          v = (col < 384) ? U_iou[k * 384 + col] : U_f[k * HD + (col - 384)];
        out[e] = f2bf(v);
    }
    *(u16x8*)&ws[(size_t)f * 8] = out;
}

// ---- XP precompute (packed bf16 u16x4 per (n,j)) + fused leaf gate math.
__global__ __launch_bounds__(512) void xp_leaf_kernel(
    const int* __restrict__ feat, const float* __restrict__ emb,
    const unsigned short* __restrict__ WT2,
    const float* __restrict__ b_iou, const float* __restrict__ b_f,
    unsigned short* __restrict__ XPb, float* __restrict__ hbuf, float* __restrict__ cbuf)
{
    __shared__ unsigned short ldsx[64 * HD];
    const int t = threadIdx.x;
    const int m0 = blockIdx.x * 64;
    {
        int r = t >> 3, c8 = t & 7;
        int n = m0 + r;
        int nn = n < NN ? n : 0;
        const float* sx = emb + (size_t)feat[nn] * HD + c8 * 16;
        float4 x0 = *(const float4*)(sx + 0);
        float4 x1 = *(const float4*)(sx + 4);
        float4 x2 = *(const float4*)(sx + 8);
        float4 x3 = *(const float4*)(sx + 12);
        lds_store8(ldsx, r, c8 * 2 + 0, x0, x1);
        lds_store8(ldsx, r, c8 * 2 + 1, x2, x3);
    }
    __syncthreads();

    const int lane = t & 63, w = t >> 6;
    const int jq = w & 3, mh = w >> 2;
    const int l15 = lane & 15, kl = lane >> 4;

    f32x4 zero = {0.f, 0.f, 0.f, 0.f};
    f32x4 acc[4][2][2];   // [gate i,o,u,f][m-tile][jt]
#pragma unroll
    for (int g = 0; g < 4; ++g)
#pragma unroll
        for (int mp = 0; mp < 2; ++mp)
#pragma unroll
            for (int jt = 0; jt < 2; ++jt) acc[g][mp][jt] = zero;

#pragma unroll
    for (int ks = 0; ks < 4; ++ks) {
        bf16x8 a0 = lds_frag(ldsx, (mh * 2 + 0) * 16 + l15, ks, kl);
        bf16x8 a1 = lds_frag(ldsx, (mh * 2 + 1) * 16 + l15, ks, kl);
#pragma unroll
        for (int g = 0; g < 4; ++g) {
#pragma unroll
            for (int jt = 0; jt < 2; ++jt) {
                bf16x8 b = frag2(WT2, g * 8 + jq * 2 + jt, ks, lane);
                acc[g][0][jt] = mfma16(a0, b, acc[g][0][jt]);
                acc[g][1][jt] = mfma16(a1, b, acc[g][1][jt]);
            }
        }
    }

#pragma unroll
    for (int mp = 0; mp < 2; ++mp) {
#pragma unroll
        for (int jt = 0; jt < 2; ++jt) {
            int j = jq * 32 + jt * 16 + l15;
            int nb = m0 + (mh * 2 + mp) * 16 + kl * 4;
            float bi = b_iou[j], bo = b_iou[HD + j], bu = b_iou[2 * HD + j], bf = b_f[j];
#pragma unroll
            for (int r = 0; r < 4; ++r) {
                int n = nb + r;
                if (n >= NN) continue;
                if (n >= LEAF_BASE) {
                    float iv = sigm(acc[0][mp][jt][r] + bi);
                    float ov = sigm(acc[1][mp][jt][r] + bo);
                    float uv = tanh_f(acc[2][mp][jt][r] + bu);
                    float cv = iv * uv;
                    cbuf[(size_t)n * HD + j] = cv;
                    hbuf[(size_t)n * HD + j] = ov * tanh_f(cv);
                } else {
                    u16x4 pk;
                    pk[0] = f2bf(acc[0][mp][jt][r] + bi);
                    pk[1] = f2bf(acc[1][mp][jt][r] + bo);
                    pk[2] = f2bf(acc[2][mp][jt][r] + bu);
                    pk[3] = f2bf(acc[3][mp][jt][r] + bf);
                    *(u16x4*)&XPb[((size_t)n * HD + j) * 4] = pk;
                }
            }
        }
    }
}

// ---- internal level body: U-projections + gates, fused. 64 nodes per pass.
__device__ __forceinline__ void level_body(
    unsigned short* lds,
    const unsigned short* __restrict__ UT2, const unsigned short* __restrict__ XPb,
    float* __restrict__ hbuf, float* __restrict__ cbuf, int base, int count, int m0)
{
    unsigned short* ldshs = lds;
    unsigned short* ldsh1 = lds + 8192;
    unsigned short* ldsh2 = lds + 16384;

    const int t = threadIdx.x;
    {
        int r = t >> 3, c8 = t & 7;
        int row = m0 + r;
        int n = base + (row < count ? row : 0);
        const float* s1 = hbuf + (size_t)(2 * n + 1) * HD + c8 * 16;
        const float* s2 = hbuf + (size_t)(2 * n + 2) * HD + c8 * 16;
        float4 p0 = *(const float4*)(s1 + 0);
        float4 p1 = *(const float4*)(s1 + 4);
        float4 p2 = *(const float4*)(s1 + 8);
        float4 p3 = *(const float4*)(s1 + 12);
        float4 q0 = *(const float4*)(s2 + 0);
        float4 q1 = *(const float4*)(s2 + 4);
        float4 q2 = *(const float4*)(s2 + 8);
        float4 q3 = *(const float4*)(s2 + 12);
        lds_store8(ldsh1, r, c8 * 2 + 0, p0, p1);
        lds_store8(ldsh1, r, c8 * 2 + 1, p2, p3);
        lds_store8(ldsh2, r, c8 * 2 + 0, q0, q1);
        lds_store8(ldsh2, r, c8 * 2 + 1, q2, q3);
        lds_store8(ldshs, r, c8 * 2 + 0, addf4(p0, q0), addf4(p1, q1));
        lds_store8(ldshs, r, c8 * 2 + 1, addf4(p2, q2), addf4(p3, q3));
    }
    __syncthreads();

    const int lane = t & 63, w = t >> 6;
    const int jq = w & 3, mh = w >> 2;
    const int l15 = lane & 15, kl = lane >> 4;

    f32x4 zero = {0.f, 0.f, 0.f, 0.f};
    f32x4 acc[5][2][2];   // i,o,u,f1,f2
#pragma unroll
    for (int g = 0; g < 5; ++g)
#pragma unroll
        for (int mp = 0; mp < 2; ++mp)
#pragma unroll
            for (int jt = 0; jt < 2; ++jt) acc[g][mp][jt] = zero;

#pragma unroll
    for (int ks = 0; ks < 4; ++ks) {
        bf16x8 ahs0 = lds_frag(ldshs, (mh * 2 + 0) * 16 + l15, ks, kl);
        bf16x8 ahs1 = lds_frag(ldshs, (mh * 2 + 1) * 16 + l15, ks, kl);
        bf16x8 ah10 = lds_frag(ldsh1, (mh * 2 + 0) * 16 + l15, ks, kl);
        bf16x8 ah11 = lds_frag(ldsh1, (mh * 2 + 1) * 16 + l15, ks, kl);
        bf16x8 ah20 = lds_frag(ldsh2, (mh * 2 + 0) * 16 + l15, ks, kl);
        bf16x8 ah21 = lds_frag(ldsh2, (mh * 2 + 1) * 16 + l15, ks, kl);
#pragma unroll
        for (int jt = 0; jt < 2; ++jt) {
            bf16x8 Bi = frag2(UT2,  0 + jq * 2 + jt, ks, lane);
            bf16x8 Bo = frag2(UT2,  8 + jq * 2 + jt, ks, lane);
            bf16x8 Bu = frag2(UT2, 16 + jq * 2 + jt, ks, lane);
            bf16x8 Bf = frag2(UT2, 24 + jq * 2 + jt, ks, lane);
            acc[0][0][jt] = mfma16(ahs0, Bi, acc[0][0][jt]);
            acc[0][1][jt] = mfma16(ahs1, Bi, acc[0][1][jt]);
            acc[1][0][jt] = mfma16(ahs0, Bo, acc[1][0][jt]);
            acc[1][1][jt] = mfma16(ahs1, Bo, acc[1][1][jt]);
            acc[2][0][jt] = mfma16(ahs0, Bu, acc[2][0][jt]);
            acc[2][1][jt] = mfma16(ahs1, Bu, acc[2][1][jt]);
            acc[3][0][jt] = mfma16(ah10, Bf, acc[3][0][jt]);
            acc[3][1][jt] = mfma16(ah11, Bf, acc[3][1][jt]);
            acc[4][0][jt] = mfma16(ah20, Bf, acc[4][0][jt]);
            acc[4][1][jt] = mfma16(ah21, Bf, acc[4][1][jt]);
        }
    }

#pragma unroll
    for (int mp = 0; mp < 2; ++mp) {
#pragma unroll
        for (int jt = 0; jt < 2; ++jt) {
            int j = jq * 32 + jt * 16 + l15;
#pragma unroll
            for (int r = 0; r < 4; ++r) {
                int row = m0 + (mh * 2 + mp) * 16 + kl * 4 + r;
                if (row >= count) continue;
                int n = base + row;
                u16x4 pk = *(const u16x4*)&XPb[((size_t)n * HD + j) * 4];
                float iv = sigm(acc[0][mp][jt][r] + bf2f(pk[0]));
                float ov = sigm(acc[1][mp][jt][r] + bf2f(pk[1]));
                float uv = tanh_f(acc[2][mp][jt][r] + bf2f(pk[2]));
                float fx = bf2f(pk[3]);
                float f1 = sigm(acc[3][mp][jt][r] + fx);
                float f2 = sigm(acc[4][mp][jt][r] + fx);
                float c1 = cbuf[(size_t)(2 * n + 1) * HD + j];
                float c2 = cbuf[(size_t)(2 * n + 2) * HD + j];
                float cn = fmaf(iv, uv, fmaf(f1, c1, f2 * c2));
                cbuf[(size_t)n * HD + j] = cn;
                hbuf[(size_t)n * HD + j] = ov * tanh_f(cn);
            }
        }
    }
}

__global__ __launch_bounds__(512) void level_u_kernel(
    const unsigned short* __restrict__ UT2, const unsigned short* __restrict__ XPb,
    float* __restrict__ hbuf, float* __restrict__ cbuf, int base, int count)
{
    __shared__ unsigned short lds[3 * 64 * HD];
    level_body(lds, UT2, XPb, hbuf, cbuf, base, count, blockIdx.x * 64);
}

// ---- fused tail v2: levels 10..16 (count 64..1), ONE workgroup, NO LDS.
// Children h/c are L1/L2-hot on this CU (written by previous pass / by the
// level-9 dispatch). A-fragments are built global->register directly (same
// f2bf arithmetic as the staged path => bit-identical results). Waves whose
// 32-row slice is entirely masked skip compute. One __syncthreads per level
// (drains vmcnt; orders pass-N writes before pass-N+1 reads on this CU).
__global__ __launch_bounds__(512) void tail_kernel2(
    const unsigned short* __restrict__ UT2, const unsigned short* __restrict__ XPb,
    float* __restrict__ hbuf, float* __restrict__ cbuf)
{
    const int t = threadIdx.x;
    const int lane = t & 63, w = t >> 6;
    const int jq = w & 3, mh = w >> 2;
    const int l15 = lane & 15, kl = lane >> 4;

    for (int lvl = 10; lvl <= 16; ++lvl) {
        const int count = 1 << (16 - lvl);
        const int base = count - 1;
        if (mh * 32 < count) {
            f32x4 zero = {0.f, 0.f, 0.f, 0.f};
            f32x4 acc[5][2][2];
#pragma unroll
            for (int g = 0; g < 5; ++g)
#pragma unroll
                for (int mp = 0; mp < 2; ++mp)
#pragma unroll
                    for (int jt = 0; jt < 2; ++jt) acc[g][mp][jt] = zero;

#pragma unroll
            for (int ks = 0; ks < 4; ++ks) {
                bf16x8 ahs[2], ah1[2], ah2[2];
#pragma unroll
                for (int mp = 0; mp < 2; ++mp) {
                    int row = mh * 32 + mp * 16 + l15;
                    int rr = row < count ? row : count - 1;
                    int n = base + rr;
                    const float* p1 = hbuf + (size_t)(2 * n + 1) * HD + ks * 32 + kl * 8;
                    const float* p2 = hbuf + (size_t)(2 * n + 2) * HD + ks * 32 + kl * 8;
                    float4 a0 = *(const float4*)p1;
                    float4 a1 = *(const float4*)(p1 + 4);
                    float4 b0 = *(const float4*)p2;
                    float4 b1 = *(const float4*)(p2 + 4);
                    ah1[mp] = pk8(a0, a1);
                    ah2[mp] = pk8(b0, b1);
                    ahs[mp] = pk8(addf4(a0, b0), addf4(a1, b1));
                }
#pragma unroll
                for (int jt = 0; jt < 2; ++jt) {
                    bf16x8 Bi = frag2(UT2,  0 + jq * 2 + jt, ks, lane);
                    bf16x8 Bo = frag2(UT2,  8 + jq * 2 + jt, ks, lane);
                    bf16x8 Bu = frag2(UT2, 16 + jq * 2 + jt, ks, lane);
                    bf16x8 Bf = frag2(UT2, 24 + jq * 2 + jt, ks, lane);
                    acc[0][0][jt] = mfma16(ahs[0], Bi, acc[0][0][jt]);
                    acc[0][1][jt] = mfma16(ahs[1], Bi, acc[0][1][jt]);
                    acc[1][0][jt] = mfma16(ahs[0], Bo, acc[1][0][jt]);
                    acc[1][1][jt] = mfma16(ahs[1], Bo, acc[1][1][jt]);
                    acc[2][0][jt] = mfma16(ahs[0], Bu, acc[2][0][jt]);
                    acc[2][1][jt] = mfma16(ahs[1], Bu, acc[2][1][jt]);
                    acc[3][0][jt] = mfma16(ah1[0], Bf, acc[3][0][jt]);
                    acc[3][1][jt] = mfma16(ah1[1], Bf, acc[3][1][jt]);
                    acc[4][0][jt] = mfma16(ah2[0], Bf, acc[4][0][jt]);
                    acc[4][1][jt] = mfma16(ah2[1], Bf, acc[4][1][jt]);
                }
            }

#pragma unroll
            for (int mp = 0; mp < 2; ++mp) {
#pragma unroll
                for (int jt = 0; jt < 2; ++jt) {
                    int j = jq * 32 + jt * 16 + l15;
#pragma unroll
                    for (int r = 0; r < 4; ++r) {
                        int row = mh * 32 + mp * 16 + kl * 4 + r;
                        if (row >= count) continue;
                        int n = base + row;
                        u16x4 pk = *(const u16x4*)&XPb[((size_t)n * HD + j) * 4];
                        float iv = sigm(acc[0][mp][jt][r] + bf2f(pk[0]));
                        float ov = sigm(acc[1][mp][jt][r] + bf2f(pk[1]));
                        float uv = tanh_f(acc[2][mp][jt][r] + bf2f(pk[2]));
                        float fx = bf2f(pk[3]);
                        float f1 = sigm(acc[3][mp][jt][r] + fx);
                        float f2 = sigm(acc[4][mp][jt][r] + fx);
                        float c1 = cbuf[(size_t)(2 * n + 1) * HD + j];
                        float c2 = cbuf[(size_t)(2 * n + 2) * HD + j];
                        float cn = fmaf(iv, uv, fmaf(f1, c1, f2 * c2));
                        cbuf[(size_t)n * HD + j] = cn;
                        hbuf[(size_t)n * HD + j] = ov * tanh_f(cn);
                    }
                }
            }
        }
        __syncthreads();
    }
}

// ---------------- scalar fallback (known-correct R3 path, used only if ws too small) ----------------
template <int MT>
__global__ __launch_bounds__(128) void leaf_kernel(
    const int* __restrict__ feat, const float* __restrict__ emb,
    const float* __restrict__ W_iou, const float* __restrict__ b_iou,
    float* __restrict__ hbuf, float* __restrict__ cbuf, int base)
{
    __shared__ float X[MT][HD];
    const int j = threadIdx.x;
    const int m0 = blockIdx.x * MT;
#pragma unroll
    for (int m = 0; m < MT; ++m) {
        int n = base + m0 + m;
        X[m][j] = emb[(size_t)feat[n] * HD + j];
    }
    __syncthreads();
    float ai[MT], ao[MT], au[MT];
#pragma unroll
    for (int m = 0; m < MT; ++m) {
        ai[m] = b_iou[j]; ao[m] = b_iou[HD + j]; au[m] = b_iou[2 * HD + j];
    }
#pragma unroll 4
    for (int k = 0; k < HD; ++k) {
        float wi = W_iou[k * 3 * HD + j];
        float wo = W_iou[k * 3 * HD + HD + j];
        float wu = W_iou[k * 3 * HD + 2 * HD + j];
#pragma unroll
        for (int m = 0; m < MT; ++m) {
            float x = X[m][k];
            ai[m] = fmaf(x, wi, ai[m]); ao[m] = fmaf(x, wo, ao[m]); au[m] = fmaf(x, wu, au[m]);
        }
    }
#pragma unroll
    for (int m = 0; m < MT; ++m) {
        int n = base + m0 + m;
        float iv = sigm(ai[m]); float ov = sigm(ao[m]); float uv = tanh_f(au[m]);
        float cv = iv * uv;
        cbuf[(size_t)n * HD + j] = cv;
        hbuf[(size_t)n * HD + j] = ov * tanh_f(cv);
    }
}

template <int MT>
__global__ __launch_bounds__(128) void level_kernel(
    const int* __restrict__ feat, const float* __restrict__ emb,
    const float* __restrict__ W_iou, const float* __restrict__ b_iou,
    const float* __restrict__ U_iou,
    const float* __restrict__ W_f, const float* __restrict__ b_f,
    const float* __restrict__ U_f,
    float* __restrict__ hbuf, float* __restrict__ cbuf, int base)
{
    __shared__ float X[MT][HD];
    __shared__ float H1[MT][HD];
    __shared__ float H2[MT][HD];
    const int j = threadIdx.x;
    const int m0 = blockIdx.x * MT;
#pragma unroll
    for (int m = 0; m < MT; ++m) {
        int n = base + m0 + m;
        X[m][j]  = emb[(size_t)feat[n] * HD + j];
        H1[m][j] = hbuf[(size_t)(2 * n + 1) * HD + j];
        H2[m][j] = hbuf[(size_t)(2 * n + 2) * HD + j];
    }
    __syncthreads();
    float ai[MT], ao[MT], au[MT], g1[MT], g2[MT];
#pragma unroll
    for (int m = 0; m < MT; ++m) {
        ai[m] = b_iou[j]; ao[m] = b_iou[HD + j]; au[m] = b_iou[2 * HD + j];
        g1[m] = b_f[j]; g2[m] = b_f[j];
    }
#pragma unroll 2
    for (int k = 0; k < HD; ++k) {
        float wi = W_iou[k * 3 * HD + j];
        float wo = W_iou[k * 3 * HD + HD + j];
        float wu = W_iou[k * 3 * HD + 2 * HD + j];
        float ui = U_iou[k * 3 * HD + j];
        float uo = U_iou[k * 3 * HD + HD + j];
        float uu = U_iou[k * 3 * HD + 2 * HD + j];
        float wf = W_f[k * HD + j];
        float uf = U_f[k * HD + j];
#pragma unroll
        for (int m = 0; m < MT; ++m) {
            float x = X[m][k]; float h1 = H1[m][k]; float h2 = H2[m][k]; float hs = h1 + h2;
            ai[m] = fmaf(x, wi, fmaf(hs, ui, ai[m]));
            ao[m] = fmaf(x, wo, fmaf(hs, uo, ao[m]));
            au[m] = fmaf(x, wu, fmaf(hs, uu, au[m]));
            g1[m] = fmaf(x, wf, fmaf(h1, uf, g1[m]));
            g2[m] = fmaf(x, wf, fmaf(h2, uf, g2[m]));
        }
    }
#pragma unroll
    for (int m = 0; m < MT; ++m) {
        int n = base + m0 + m;
        float iv = sigm(ai[m]); float ov = sigm(ao[m]); float uv = tanh_f(au[m]);
        float f1 = sigm(g1[m]); float f2 = sigm(g2[m]);
        float c1 = cbuf[(size_t)(2 * n + 1) * HD + j];
        float c2 = cbuf[(size_t)(2 * n + 2) * HD + j];
        float cn = fmaf(iv, uv, fmaf(f1, c1, f2 * c2));
        cbuf[(size_t)n * HD + j] = cn;
        hbuf[(size_t)n * HD + j] = ov * tanh_f(cn);
    }
}

extern "C" void kernel_launch(void* const* d_in, const int* in_sizes, int n_in,
                              void* d_out, int out_size, void* d_ws, size_t ws_size,
                              hipStream_t stream)
{
    const int*   feat  = (const int*)d_in[0];
    const float* emb   = (const float*)d_in[4];
    const float* W_iou = (const float*)d_in[5];
    const float* b_iou = (const float*)d_in[6];
    const float* U_iou = (const float*)d_in[7];
    const float* W_f   = (const float*)d_in[8];
    const float* b_f   = (const float*)d_in[9];
    const float* U_f   = (const float*)d_in[10];

    float* hbuf = (float*)d_out;
    float* cbuf = hbuf + (size_t)NN * HD;

    const size_t PACK_BYTES = 2u * 65536u * 2u;                      // 256 KB (WT2+UT2)
    const size_t XP_BYTES   = (size_t)N_INTERNAL * HD * 4 * 2;       // ~67 MB (bf16 x4 gates)
    if (ws_size >= PACK_BYTES + XP_BYTES) {
        unsigned short* wpk = (unsigned short*)d_ws;
        const unsigned short* WT2 = wpk;
        const unsigned short* UT2 = wpk + 65536;
        unsigned short* XPb = (unsigned short*)((char*)d_ws + PACK_BYTES);

        build_packed<<<64, 256, 0, stream>>>(W_iou, U_iou, W_f, U_f, wpk);
        xp_leaf_kernel<<<2048, 512, 0, stream>>>(feat, emb, WT2, b_iou, b_f, XPb, hbuf, cbuf);

        for (int lvl = 1; lvl <= 9; ++lvl) {
            const int count = 1 << (16 - lvl);
            const int base  = count - 1;
            level_u_kernel<<<count / 64, 512, 0, stream>>>(UT2, XPb, hbuf, cbuf, base, count);
        }
        tail_kernel2<<<1, 512, 0, stream>>>(UT2, XPb, hbuf, cbuf);
    } else {
        // fallback: scalar path (correct, slower)
        leaf_kernel<16><<<65536 / 16, 128, 0, stream>>>(feat, emb, W_iou, b_iou, hbuf, cbuf, 65535);
        for (int lvl = 1; lvl <= 16; ++lvl) {
            const int d = 16 - lvl;
            const int count = 1 << d;
            const int base = count - 1;
            if (count >= 16) {
                level_kernel<16><<<count / 16, 128, 0, stream>>>(
                    feat, emb, W_iou, b_iou, U_iou, W_f, b_f, U_f, hbuf, cbuf, base);
            } else if (count == 8) {
                level_kernel<8><<<1, 128, 0, stream>>>(
                    feat, emb, W_iou, b_iou, U_iou, W_f, b_f, U_f, hbuf, cbuf, base);
            } else if (count == 4) {
                level_kernel<4><<<1, 128, 0, stream>>>(
                    feat, emb, W_iou, b_iou, U_iou, W_f, b_f, U_f, hbuf, cbuf, base);
            } else if (count == 2) {
                level_kernel<2><<<1, 128, 0, stream>>>(
                    feat, emb, W_iou, b_iou, U_iou, W_f, b_f, U_f, hbuf, cbuf, base);
            } else {
                level_kernel<1><<<1, 128, 0, stream>>>(
                    feat, emb, W_iou, b_iou, U_iou, W_f, b_f, U_f, hbuf, cbuf, base);
            }
        }
    }
}

// Round 9
// 290.687 us; speedup vs baseline: 4.0624x; 1.0622x over previous
//
#include <hip/hip_runtime.h>
#include <math.h>

#define NN 131071
#define HD 128
#define N_INTERNAL 65535
#define LEAF_BASE 65535

typedef short bf16x8 __attribute__((ext_vector_type(8)));
typedef unsigned short u16x8 __attribute__((ext_vector_type(8)));
typedef unsigned short u16x4 __attribute__((ext_vector_type(4)));
typedef float f32x4 __attribute__((ext_vector_type(4)));

__device__ __forceinline__ float sigm(float z) { return 1.0f / (1.0f + __expf(-z)); }
__device__ __forceinline__ float tanh_f(float z) { return 1.0f - 2.0f / (__expf(2.0f * z) + 1.0f); }

__device__ __forceinline__ unsigned short f2bf(float f) {
    unsigned u = __float_as_uint(f);
    u += 0x7FFFu + ((u >> 16) & 1u);
    return (unsigned short)(u >> 16);
}
__device__ __forceinline__ float bf2f(unsigned short b) {
    return __uint_as_float(((unsigned)b) << 16);
}

__device__ __forceinline__ f32x4 mfma16(bf16x8 a, bf16x8 b, f32x4 c) {
    return __builtin_amdgcn_mfma_f32_16x16x32_bf16(a, b, c, 0, 0, 0);
}

__device__ __forceinline__ float4 addf4(float4 a, float4 b) {
    float4 r; r.x = a.x + b.x; r.y = a.y + b.y; r.z = a.z + b.z; r.w = a.w + b.w; return r;
}

// pack two float4 into a bf16x8 fragment (round-to-nearest-even)
__device__ __forceinline__ bf16x8 pk8(float4 a, float4 b) {
    u16x8 p;
    p[0] = f2bf(a.x); p[1] = f2bf(a.y); p[2] = f2bf(a.z); p[3] = f2bf(a.w);
    p[4] = f2bf(b.x); p[5] = f2bf(b.y); p[6] = f2bf(b.z); p[7] = f2bf(b.w);
    return *(bf16x8*)&p;
}

// store 8 f32 (two float4) as bf16 chunk cc (16B) of row r, XOR-swizzled
__device__ __forceinline__ void lds_store8(unsigned short* region, int r, int cc, float4 a, float4 b) {
    u16x8 p;
    p[0] = f2bf(a.x); p[1] = f2bf(a.y); p[2] = f2bf(a.z); p[3] = f2bf(a.w);
    p[4] = f2bf(b.x); p[5] = f2bf(b.y); p[6] = f2bf(b.z); p[7] = f2bf(b.w);
    *(u16x8*)&region[r * HD + ((cc ^ (r & 7)) << 3)] = p;
}

// A-fragment: row, k-step ks, k-lane kl (16B), swizzled
__device__ __forceinline__ bf16x8 lds_frag(const unsigned short* region, int row, int ks, int kl) {
    int cc = ks * 4 + kl;
    return *(const bf16x8*)&region[row * HD + ((cc ^ (row & 7)) << 3)];
}

// B-fragment from fragment-order-packed weights: contiguous 16B per lane
__device__ __forceinline__ bf16x8 frag2(const unsigned short* M, int ct, int ks, int lane) {
    return *(const bf16x8*)&M[(((ct * 4 + ks) * 64) + lane) * 8];
}

// ---- pack bf16 weights in MFMA-fragment order.
// WT2 (matrix 0): cols 0:384 = W_iou, 384:512 = W_f.  UT2 (matrix 1): U_iou | U_f.
__global__ __launch_bounds__(256) void build_packed(
    const float* __restrict__ W_iou, const float* __restrict__ U_iou,
    const float* __restrict__ W_f, const float* __restrict__ U_f,
    unsigned short* __restrict__ ws)
{
    int f = blockIdx.x * 256 + threadIdx.x;   // 0..16383
    int mat = f >> 13;
    int rem = f & 8191;
    int ct = rem >> 8;
    int ks = (rem >> 6) & 3;
    int lane = rem & 63;
    int col = ct * 16 + (lane & 15);
    int k0 = ks * 32 + (lane >> 4) * 8;
    u16x8 out;
#pragma unroll
    for (int e = 0; e < 8; ++e) {
        int k = k0 + e;
        float v;
        if (mat == 0) v = (col < 384) ? W_iou[k * 384 + col] : W_f[k * HD + (col - 384)];
        else          v = (col < 384) ? U_iou[k * 384 + col] : U_f[k * HD + (col - 384)];
        out[e] = f2bf(v);
    }
    *(u16x8*)&ws[(size_t)f * 8] = out;
}

// ---- XP precompute (packed bf16 u16x4 per (n,j)) + fused leaf gate math.
__global__ __launch_bounds__(512) void xp_leaf_kernel(
    const int* __restrict__ feat, const float* __restrict__ emb,
    const unsigned short* __restrict__ WT2,
    const float* __restrict__ b_iou, const float* __restrict__ b_f,
    unsigned short* __restrict__ XPb, float* __restrict__ hbuf, float* __restrict__ cbuf)
{
    __shared__ unsigned short ldsx[64 * HD];
    const int t = threadIdx.x;
    const int m0 = blockIdx.x * 64;
    {
        int r = t >> 3, c8 = t & 7;
        int n = m0 + r;
        int nn = n < NN ? n : 0;
        const float* sx = emb + (size_t)feat[nn] * HD + c8 * 16;
        float4 x0 = *(const float4*)(sx + 0);
        float4 x1 = *(const float4*)(sx + 4);
        float4 x2 = *(const float4*)(sx + 8);
        float4 x3 = *(const float4*)(sx + 12);
        lds_store8(ldsx, r, c8 * 2 + 0, x0, x1);
        lds_store8(ldsx, r, c8 * 2 + 1, x2, x3);
    }
    __syncthreads();

    const int lane = t & 63, w = t >> 6;
    const int jq = w & 3, mh = w >> 2;
    const int l15 = lane & 15, kl = lane >> 4;

    f32x4 zero = {0.f, 0.f, 0.f, 0.f};
    f32x4 acc[4][2][2];   // [gate i,o,u,f][m-tile][jt]
#pragma unroll
    for (int g = 0; g < 4; ++g)
#pragma unroll
        for (int mp = 0; mp < 2; ++mp)
#pragma unroll
            for (int jt = 0; jt < 2; ++jt) acc[g][mp][jt] = zero;

#pragma unroll
    for (int ks = 0; ks < 4; ++ks) {
        bf16x8 a0 = lds_frag(ldsx, (mh * 2 + 0) * 16 + l15, ks, kl);
        bf16x8 a1 = lds_frag(ldsx, (mh * 2 + 1) * 16 + l15, ks, kl);
#pragma unroll
        for (int g = 0; g < 4; ++g) {
#pragma unroll
            for (int jt = 0; jt < 2; ++jt) {
                bf16x8 b = frag2(WT2, g * 8 + jq * 2 + jt, ks, lane);
                acc[g][0][jt] = mfma16(a0, b, acc[g][0][jt]);
                acc[g][1][jt] = mfma16(a1, b, acc[g][1][jt]);
            }
        }
    }

#pragma unroll
    for (int mp = 0; mp < 2; ++mp) {
#pragma unroll
        for (int jt = 0; jt < 2; ++jt) {
            int j = jq * 32 + jt * 16 + l15;
            int nb = m0 + (mh * 2 + mp) * 16 + kl * 4;
            float bi = b_iou[j], bo = b_iou[HD + j], bu = b_iou[2 * HD + j], bf = b_f[j];
#pragma unroll
            for (int r = 0; r < 4; ++r) {
                int n = nb + r;
                if (n >= NN) continue;
                if (n >= LEAF_BASE) {
                    float iv = sigm(acc[0][mp][jt][r] + bi);
                    float ov = sigm(acc[1][mp][jt][r] + bo);
                    float uv = tanh_f(acc[2][mp][jt][r] + bu);
                    float cv = iv * uv;
                    cbuf[(size_t)n * HD + j] = cv;
                    hbuf[(size_t)n * HD + j] = ov * tanh_f(cv);
                } else {
                    u16x4 pk;
                    pk[0] = f2bf(acc[0][mp][jt][r] + bi);
                    pk[1] = f2bf(acc[1][mp][jt][r] + bo);
                    pk[2] = f2bf(acc[2][mp][jt][r] + bu);
                    pk[3] = f2bf(acc[3][mp][jt][r] + bf);
                    *(u16x4*)&XPb[((size_t)n * HD + j) * 4] = pk;
                }
            }
        }
    }
}

// ---- internal level body: U-projections + gates, fused. 64 nodes per pass.
__device__ __forceinline__ void level_body(
    unsigned short* lds,
    const unsigned short* __restrict__ UT2, const unsigned short* __restrict__ XPb,
    float* __restrict__ hbuf, float* __restrict__ cbuf, int base, int count, int m0)
{
    unsigned short* ldshs = lds;
    unsigned short* ldsh1 = lds + 8192;
    unsigned short* ldsh2 = lds + 16384;

    const int t = threadIdx.x;
    {
        int r = t >> 3, c8 = t & 7;
        int row = m0 + r;
        int n = base + (row < count ? row : 0);
        const float* s1 = hbuf + (size_t)(2 * n + 1) * HD + c8 * 16;
        const float* s2 = hbuf + (size_t)(2 * n + 2) * HD + c8 * 16;
        float4 p0 = *(const float4*)(s1 + 0);
        float4 p1 = *(const float4*)(s1 + 4);
        float4 p2 = *(const float4*)(s1 + 8);
        float4 p3 = *(const float4*)(s1 + 12);
        float4 q0 = *(const float4*)(s2 + 0);
        float4 q1 = *(const float4*)(s2 + 4);
        float4 q2 = *(const float4*)(s2 + 8);
        float4 q3 = *(const float4*)(s2 + 12);
        lds_store8(ldsh1, r, c8 * 2 + 0, p0, p1);
        lds_store8(ldsh1, r, c8 * 2 + 1, p2, p3);
        lds_store8(ldsh2, r, c8 * 2 + 0, q0, q1);
        lds_store8(ldsh2, r, c8 * 2 + 1, q2, q3);
        lds_store8(ldshs, r, c8 * 2 + 0, addf4(p0, q0), addf4(p1, q1));
        lds_store8(ldshs, r, c8 * 2 + 1, addf4(p2, q2), addf4(p3, q3));
    }
    __syncthreads();

    const int lane = t & 63, w = t >> 6;
    const int jq = w & 3, mh = w >> 2;
    const int l15 = lane & 15, kl = lane >> 4;

    f32x4 zero = {0.f, 0.f, 0.f, 0.f};
    f32x4 acc[5][2][2];   // i,o,u,f1,f2
#pragma unroll
    for (int g = 0; g < 5; ++g)
#pragma unroll
        for (int mp = 0; mp < 2; ++mp)
#pragma unroll
            for (int jt = 0; jt < 2; ++jt) acc[g][mp][jt] = zero;

#pragma unroll
    for (int ks = 0; ks < 4; ++ks) {
        bf16x8 ahs0 = lds_frag(ldshs, (mh * 2 + 0) * 16 + l15, ks, kl);
        bf16x8 ahs1 = lds_frag(ldshs, (mh * 2 + 1) * 16 + l15, ks, kl);
        bf16x8 ah10 = lds_frag(ldsh1, (mh * 2 + 0) * 16 + l15, ks, kl);
        bf16x8 ah11 = lds_frag(ldsh1, (mh * 2 + 1) * 16 + l15, ks, kl);
        bf16x8 ah20 = lds_frag(ldsh2, (mh * 2 + 0) * 16 + l15, ks, kl);
        bf16x8 ah21 = lds_frag(ldsh2, (mh * 2 + 1) * 16 + l15, ks, kl);
#pragma unroll
        for (int jt = 0; jt < 2; ++jt) {
            bf16x8 Bi = frag2(UT2,  0 + jq * 2 + jt, ks, lane);
            bf16x8 Bo = frag2(UT2,  8 + jq * 2 + jt, ks, lane);
            bf16x8 Bu = frag2(UT2, 16 + jq * 2 + jt, ks, lane);
            bf16x8 Bf = frag2(UT2, 24 + jq * 2 + jt, ks, lane);
            acc[0][0][jt] = mfma16(ahs0, Bi, acc[0][0][jt]);
            acc[0][1][jt] = mfma16(ahs1, Bi, acc[0][1][jt]);
            acc[1][0][jt] = mfma16(ahs0, Bo, acc[1][0][jt]);
            acc[1][1][jt] = mfma16(ahs1, Bo, acc[1][1][jt]);
            acc[2][0][jt] = mfma16(ahs0, Bu, acc[2][0][jt]);
            acc[2][1][jt] = mfma16(ahs1, Bu, acc[2][1][jt]);
            acc[3][0][jt] = mfma16(ah10, Bf, acc[3][0][jt]);
            acc[3][1][jt] = mfma16(ah11, Bf, acc[3][1][jt]);
            acc[4][0][jt] = mfma16(ah20, Bf, acc[4][0][jt]);
            acc[4][1][jt] = mfma16(ah21, Bf, acc[4][1][jt]);
        }
    }

#pragma unroll
    for (int mp = 0; mp < 2; ++mp) {
#pragma unroll
        for (int jt = 0; jt < 2; ++jt) {
            int j = jq * 32 + jt * 16 + l15;
#pragma unroll
            for (int r = 0; r < 4; ++r) {
                int row = m0 + (mh * 2 + mp) * 16 + kl * 4 + r;
                if (row >= count) continue;
                int n = base + row;
                u16x4 pk = *(const u16x4*)&XPb[((size_t)n * HD + j) * 4];
                float iv = sigm(acc[0][mp][jt][r] + bf2f(pk[0]));
                float ov = sigm(acc[1][mp][jt][r] + bf2f(pk[1]));
                float uv = tanh_f(acc[2][mp][jt][r] + bf2f(pk[2]));
                float fx = bf2f(pk[3]);
                float f1 = sigm(acc[3][mp][jt][r] + fx);
                float f2 = sigm(acc[4][mp][jt][r] + fx);
                float c1 = cbuf[(size_t)(2 * n + 1) * HD + j];
                float c2 = cbuf[(size_t)(2 * n + 2) * HD + j];
                float cn = fmaf(iv, uv, fmaf(f1, c1, f2 * c2));
                cbuf[(size_t)n * HD + j] = cn;
                hbuf[(size_t)n * HD + j] = ov * tanh_f(cn);
            }
        }
    }
}

__global__ __launch_bounds__(512) void level_u_kernel(
    const unsigned short* __restrict__ UT2, const unsigned short* __restrict__ XPb,
    float* __restrict__ hbuf, float* __restrict__ cbuf, int base, int count)
{
    __shared__ unsigned short lds[3 * 64 * HD];
    level_body(lds, UT2, XPb, hbuf, cbuf, base, count, blockIdx.x * 64);
}

// ---- fused tail v3: levels 10..16 (count 64..1), ONE workgroup.
// h for nodes 0..254 lives in LDS as bf16 in A-fragment layout for the whole
// kernel: A-frags need NO conversion VALU, and the inter-level h dependency
// never round-trips global memory. hs=h1+h2 is realized via MFMA linearity
// (mfma(h1,B)+mfma(h2,B), f32 accumulate) -- no pack/add VALU, tighter
// numerics than rounding the sum. c stays f32 in global (bit-identical math).
// Level loop kept rolled (#pragma unroll 1) to keep the code I-cache small.
__global__ __launch_bounds__(512) void tail_kernel3(
    const unsigned short* __restrict__ UT2, const unsigned short* __restrict__ XPb,
    float* __restrict__ hbuf, float* __restrict__ cbuf)
{
    __shared__ unsigned short hlds[255 * HD];   // 65280 B, nodes 0..254
    const int t = threadIdx.x;

    // prologue: level-9 outputs (nodes 127..254) f32 -> bf16 LDS, swizzled
    {
        int n = 127 + (t >> 2);       // 512 threads / 4 per node = 128 nodes
        int c0 = (t & 3) * 32;        // 32-col chunk
        const float* src = hbuf + (size_t)n * HD + c0;
#pragma unroll
        for (int q = 0; q < 4; ++q) {
            float4 a = *(const float4*)(src + q * 8);
            float4 b = *(const float4*)(src + q * 8 + 4);
            int cc = (c0 >> 3) + q;
            *(bf16x8*)&hlds[n * HD + ((cc ^ (n & 7)) << 3)] = pk8(a, b);
        }
    }
    __syncthreads();

    const int lane = t & 63, w = t >> 6;
    const int jq = w & 3, mh = w >> 2;
    const int l15 = lane & 15, kl = lane >> 4;

#pragma unroll 1
    for (int lvl = 10; lvl <= 16; ++lvl) {
        const int count = 1 << (16 - lvl);
        const int base = count - 1;
        if (mh * 32 < count) {
            f32x4 zero = {0.f, 0.f, 0.f, 0.f};
            f32x4 acc[5][2][2];
#pragma unroll
            for (int g = 0; g < 5; ++g)
#pragma unroll
                for (int mp = 0; mp < 2; ++mp)
#pragma unroll
                    for (int jt = 0; jt < 2; ++jt) acc[g][mp][jt] = zero;

#pragma unroll
            for (int ks = 0; ks < 4; ++ks) {
                bf16x8 ah1[2], ah2[2];
#pragma unroll
                for (int mp = 0; mp < 2; ++mp) {
                    int row = mh * 32 + mp * 16 + l15;
                    int rr = row < count ? row : count - 1;
                    int n = base + rr;
                    ah1[mp] = lds_frag(hlds, 2 * n + 1, ks, kl);
                    ah2[mp] = lds_frag(hlds, 2 * n + 2, ks, kl);
                }
#pragma unroll
                for (int jt = 0; jt < 2; ++jt) {
                    bf16x8 Bi = frag2(UT2,  0 + jq * 2 + jt, ks, lane);
                    bf16x8 Bo = frag2(UT2,  8 + jq * 2 + jt, ks, lane);
                    bf16x8 Bu = frag2(UT2, 16 + jq * 2 + jt, ks, lane);
                    bf16x8 Bf = frag2(UT2, 24 + jq * 2 + jt, ks, lane);
#pragma unroll
                    for (int mp = 0; mp < 2; ++mp) {
                        // iou gates: mfma(h1,B)+mfma(h2,B)  (== hs @ B, f32 acc)
                        acc[0][mp][jt] = mfma16(ah1[mp], Bi, mfma16(ah2[mp], Bi, acc[0][mp][jt]));
                        acc[1][mp][jt] = mfma16(ah1[mp], Bo, mfma16(ah2[mp], Bo, acc[1][mp][jt]));
                        acc[2][mp][jt] = mfma16(ah1[mp], Bu, mfma16(ah2[mp], Bu, acc[2][mp][jt]));
                        acc[3][mp][jt] = mfma16(ah1[mp], Bf, acc[3][mp][jt]);
                        acc[4][mp][jt] = mfma16(ah2[mp], Bf, acc[4][mp][jt]);
                    }
                }
            }

#pragma unroll
            for (int mp = 0; mp < 2; ++mp) {
#pragma unroll
                for (int jt = 0; jt < 2; ++jt) {
                    int j = jq * 32 + jt * 16 + l15;
#pragma unroll
                    for (int r = 0; r < 4; ++r) {
                        int row = mh * 32 + mp * 16 + kl * 4 + r;
                        if (row >= count) continue;
                        int n = base + row;
                        u16x4 pk = *(const u16x4*)&XPb[((size_t)n * HD + j) * 4];
                        float iv = sigm(acc[0][mp][jt][r] + bf2f(pk[0]));
                        float ov = sigm(acc[1][mp][jt][r] + bf2f(pk[1]));
                        float uv = tanh_f(acc[2][mp][jt][r] + bf2f(pk[2]));
                        float fx = bf2f(pk[3]);
                        float f1 = sigm(acc[3][mp][jt][r] + fx);
                        float f2 = sigm(acc[4][mp][jt][r] + fx);
                        float c1 = cbuf[(size_t)(2 * n + 1) * HD + j];
                        float c2 = cbuf[(size_t)(2 * n + 2) * HD + j];
                        float cn = fmaf(iv, uv, fmaf(f1, c1, f2 * c2));
                        float hn = ov * tanh_f(cn);
                        cbuf[(size_t)n * HD + j] = cn;
                        hbuf[(size_t)n * HD + j] = hn;
                        // h bf16 -> LDS (A-frag layout) for the next level
                        int cc = j >> 3;
                        hlds[n * HD + ((cc ^ (n & 7)) << 3) + (j & 7)] = f2bf(hn);
                    }
                }
            }
        }
        __syncthreads();
    }
}

// ---------------- scalar fallback (known-correct R3 path, used only if ws too small) ----------------
template <int MT>
__global__ __launch_bounds__(128) void leaf_kernel(
    const int* __restrict__ feat, const float* __restrict__ emb,
    const float* __restrict__ W_iou, const float* __restrict__ b_iou,
    float* __restrict__ hbuf, float* __restrict__ cbuf, int base)
{
    __shared__ float X[MT][HD];
    const int j = threadIdx.x;
    const int m0 = blockIdx.x * MT;
#pragma unroll
    for (int m = 0; m < MT; ++m) {
        int n = base + m0 + m;
        X[m][j] = emb[(size_t)feat[n] * HD + j];
    }
    __syncthreads();
    float ai[MT], ao[MT], au[MT];
#pragma unroll
    for (int m = 0; m < MT; ++m) {
        ai[m] = b_iou[j]; ao[m] = b_iou[HD + j]; au[m] = b_iou[2 * HD + j];
    }
#pragma unroll 4
    for (int k = 0; k < HD; ++k) {
        float wi = W_iou[k * 3 * HD + j];
        float wo = W_iou[k * 3 * HD + HD + j];
        float wu = W_iou[k * 3 * HD + 2 * HD + j];
#pragma unroll
        for (int m = 0; m < MT; ++m) {
            float x = X[m][k];
            ai[m] = fmaf(x, wi, ai[m]); ao[m] = fmaf(x, wo, ao[m]); au[m] = fmaf(x, wu, au[m]);
        }
    }
#pragma unroll
    for (int m = 0; m < MT; ++m) {
        int n = base + m0 + m;
        float iv = sigm(ai[m]); float ov = sigm(ao[m]); float uv = tanh_f(au[m]);
        float cv = iv * uv;
        cbuf[(size_t)n * HD + j] = cv;
        hbuf[(size_t)n * HD + j] = ov * tanh_f(cv);
    }
}

template <int MT>
__global__ __launch_bounds__(128) void level_kernel(
    const int* __restrict__ feat, const float* __restrict__ emb,
    const float* __restrict__ W_iou, const float* __restrict__ b_iou,
    const float* __restrict__ U_iou,
    const float* __restrict__ W_f, const float* __restrict__ b_f,
    const float* __restrict__ U_f,
    float* __restrict__ hbuf, float* __restrict__ cbuf, int base)
{
    __shared__ float X[MT][HD];
    __shared__ float H1[MT][HD];
    __shared__ float H2[MT][HD];
    const int j = threadIdx.x;
    const int m0 = blockIdx.x * MT;
#pragma unroll
    for (int m = 0; m < MT; ++m) {
        int n = base + m0 + m;
        X[m][j]  = emb[(size_t)feat[n] * HD + j];
        H1[m][j] = hbuf[(size_t)(2 * n + 1) * HD + j];
        H2[m][j] = hbuf[(size_t)(2 * n + 2) * HD + j];
    }
    __syncthreads();
    float ai[MT], ao[MT], au[MT], g1[MT], g2[MT];
#pragma unroll
    for (int m = 0; m < MT; ++m) {
        ai[m] = b_iou[j]; ao[m] = b_iou[HD + j]; au[m] = b_iou[2 * HD + j];
        g1[m] = b_f[j]; g2[m] = b_f[j];
    }
#pragma unroll 2
    for (int k = 0; k < HD; ++k) {
        float wi = W_iou[k * 3 * HD + j];
        float wo = W_iou[k * 3 * HD + HD + j];
        float wu = W_iou[k * 3 * HD + 2 * HD + j];
        float ui = U_iou[k * 3 * HD + j];
        float uo = U_iou[k * 3 * HD + HD + j];
        float uu = U_iou[k * 3 * HD + 2 * HD + j];
        float wf = W_f[k * HD + j];
        float uf = U_f[k * HD + j];
#pragma unroll
        for (int m = 0; m < MT; ++m) {
            float x = X[m][k]; float h1 = H1[m][k]; float h2 = H2[m][k]; float hs = h1 + h2;
            ai[m] = fmaf(x, wi, fmaf(hs, ui, ai[m]));
            ao[m] = fmaf(x, wo, fmaf(hs, uo, ao[m]));
            au[m] = fmaf(x, wu, fmaf(hs, uu, au[m]));
            g1[m] = fmaf(x, wf, fmaf(h1, uf, g1[m]));
            g2[m] = fmaf(x, wf, fmaf(h2, uf, g2[m]));
        }
    }
#pragma unroll
    for (int m = 0; m < MT; ++m) {
        int n = base + m0 + m;
        float iv = sigm(ai[m]); float ov = sigm(ao[m]); float uv = tanh_f(au[m]);
        float f1 = sigm(g1[m]); float f2 = sigm(g2[m]);
        float c1 = cbuf[(size_t)(2 * n + 1) * HD + j];
        float c2 = cbuf[(size_t)(2 * n + 2) * HD + j];
        float cn = fmaf(iv, uv, fmaf(f1, c1, f2 * c2));
        cbuf[(size_t)n * HD + j] = cn;
        hbuf[(size_t)n * HD + j] = ov * tanh_f(cn);
    }
}

extern "C" void kernel_launch(void* const* d_in, const int* in_sizes, int n_in,
                              void* d_out, int out_size, void* d_ws, size_t ws_size,
                              hipStream_t stream)
{
    const int*   feat  = (const int*)d_in[0];
    const float* emb   = (const float*)d_in[4];
    const float* W_iou = (const float*)d_in[5];
    const float* b_iou = (const float*)d_in[6];
    const float* U_iou = (const float*)d_in[7];
    const float* W_f   = (const float*)d_in[8];
    const float* b_f   = (const float*)d_in[9];
    const float* U_f   = (const float*)d_in[10];

    float* hbuf = (float*)d_out;
    float* cbuf = hbuf + (size_t)NN * HD;

    const size_t PACK_BYTES = 2u * 65536u * 2u;                      // 256 KB (WT2+UT2)
    const size_t XP_BYTES   = (size_t)N_INTERNAL * HD * 4 * 2;       // ~67 MB (bf16 x4 gates)
    if (ws_size >= PACK_BYTES + XP_BYTES) {
        unsigned short* wpk = (unsigned short*)d_ws;
        const unsigned short* WT2 = wpk;
        const unsigned short* UT2 = wpk + 65536;
        unsigned short* XPb = (unsigned short*)((char*)d_ws + PACK_BYTES);

        build_packed<<<64, 256, 0, stream>>>(W_iou, U_iou, W_f, U_f, wpk);
        xp_leaf_kernel<<<2048, 512, 0, stream>>>(feat, emb, WT2, b_iou, b_f, XPb, hbuf, cbuf);

        for (int lvl = 1; lvl <= 9; ++lvl) {
            const int count = 1 << (16 - lvl);
            const int base  = count - 1;
            level_u_kernel<<<count / 64, 512, 0, stream>>>(UT2, XPb, hbuf, cbuf, base, count);
        }
        tail_kernel3<<<1, 512, 0, stream>>>(UT2, XPb, hbuf, cbuf);
    } else {
        // fallback: scalar path (correct, slower)
        leaf_kernel<16><<<65536 / 16, 128, 0, stream>>>(feat, emb, W_iou, b_iou, hbuf, cbuf, 65535);
        for (int lvl = 1; lvl <= 16; ++lvl) {
            const int d = 16 - lvl;
            const int count = 1 << d;
            const int base = count - 1;
            if (count >= 16) {
                level_kernel<16><<<count / 16, 128, 0, stream>>>(
                    feat, emb, W_iou, b_iou, U_iou, W_f, b_f, U_f, hbuf, cbuf, base);
            } else if (count == 8) {
                level_kernel<8><<<1, 128, 0, stream>>>(
                    feat, emb, W_iou, b_iou, U_iou, W_f, b_f, U_f, hbuf, cbuf, base);
            } else if (count == 4) {
                level_kernel<4><<<1, 128, 0, stream>>>(
                    feat, emb, W_iou, b_iou, U_iou, W_f, b_f, U_f, hbuf, cbuf, base);
            } else if (count == 2) {
                level_kernel<2><<<1, 128, 0, stream>>>(
                    feat, emb, W_iou, b_iou, U_iou, W_f, b_f, U_f, hbuf, cbuf, base);
            } else {
                level_kernel<1><<<1, 128, 0, stream>>>(
                    feat, emb, W_iou, b_iou, U_iou, W_f, b_f, U_f, hbuf, cbuf, base);
            }
        }
    }
}